// Round 3
// baseline (1535.776 us; speedup 1.0000x reference)
//
#include <hip/hip_runtime.h>
#include <cstdint>

#define DIVUP(a,b) (((a)+(b)-1)/(b))

typedef __attribute__((ext_vector_type(4))) float f32x4;
typedef __attribute__((ext_vector_type(8))) _Float16 half8;

// Direct global->LDS DMA, 16B per lane. LDS dest is WAVE-UNIFORM base + lane*16.
__device__ __forceinline__ void gload_lds16(const void* g, void* l) {
  __builtin_amdgcn_global_load_lds(
      (const __attribute__((address_space(1))) void*)g,
      (__attribute__((address_space(3))) void*)l, 16, 0, 0);
}

__device__ __forceinline__ float cubicw(float x) {
  // PyTorch bicubic kernel, a = -0.75
  float ax = fabsf(x);
  float ax2 = ax * ax;
  float ax3 = ax2 * ax;
  if (ax <= 1.0f) return 1.25f * ax3 - 2.25f * ax2 + 1.0f;
  if (ax < 2.0f)  return -0.75f * ax3 + 3.75f * ax2 - 6.0f * ax + 3.0f;
  return 0.0f;
}

// S[b,pix] = sum_c x[b,c,pix]^2
__global__ void sumsq_kernel(const float* __restrict__ x, float* __restrict__ S,
                             int C, int HW, int total) {
  int i = blockIdx.x * blockDim.x + threadIdx.x;
  if (i >= total) return;
  int pix = i % HW, b = i / HW;
  const float* p = x + (size_t)b * C * HW + pix;
  float s = 0.f;
  for (int c = 0; c < C; ++c) { float v = p[(size_t)c * HW]; s += v * v; }
  S[i] = s;
}

// invn[b,p] = 1 / max(sqrt(3x3 zero-padded window sum of S), 1e-12)
__global__ void invnorm_kernel(const float* __restrict__ S, float* __restrict__ invn,
                               int H, int W, int total) {
  int i = blockIdx.x * blockDim.x + threadIdx.x;
  if (i >= total) return;
  int p = i % (H * W), b = i / (H * W);
  int ph = p / W, pw = p % W;
  const float* Sb = S + (size_t)b * H * W;
  float s = 0.f;
  for (int ki = 0; ki < 3; ++ki) {
    int y = ph + ki - 1;
    if (y < 0 || y >= H) continue;
    for (int kj = 0; kj < 3; ++kj) {
      int xx = pw + kj - 1;
      if (xx < 0 || xx >= W) continue;
      s += Sb[y * W + xx];
    }
  }
  float n = fmaxf(sqrtf(s), 1e-12f);
  invn[i] = 1.0f / n;
}

// l-layout descriptors (fp32, D-major) for levels 1/2
__global__ void desc_l_kernel(const float* __restrict__ x, const float* __restrict__ invn,
                              float* __restrict__ out, int C, int H, int W, int total) {
  int i = blockIdx.x * blockDim.x + threadIdx.x;
  if (i >= total) return;
  int HW = H * W, D = C * 9;
  int p = i % HW;
  int d = (i / HW) % D;
  int b = i / (HW * D);
  int c = d / 9, r = d % 9, ki = r / 3, kj = r % 3;
  int ph = p / W, pw = p % W;
  int y = ph + ki - 1, xx = pw + kj - 1;
  float v = 0.f;
  if (y >= 0 && y < H && xx >= 0 && xx < W) v = x[((size_t)(b * C + c) * H + y) * W + xx];
  out[i] = v * invn[b * HW + p];
}

// r-layout descriptors (fp32, N-major) for levels 1/2
__global__ void desc_r_kernel(const float* __restrict__ x, const float* __restrict__ invn,
                              float* __restrict__ out, int C, int H, int W, int total) {
  int i = blockIdx.x * blockDim.x + threadIdx.x;
  if (i >= total) return;
  int HW = H * W, D = C * 9;
  int d = i % D;
  int p = (i / D) % HW;
  int b = i / (D * HW);
  int c = d / 9, r = d % 9, ki = r / 3, kj = r % 3;
  int ph = p / W, pw = p % W;
  int y = ph + ki - 1, xx = pw + kj - 1;
  float v = 0.f;
  if (y >= 0 && y < H && xx >= 0 && xx < W) v = x[((size_t)(b * C + c) * H + y) * W + xx];
  out[i] = v * invn[b * HW + p];
}

// Level-3 split-f16 descriptors, pixel-major [B][4096][576]:
// hi = f16(v), lo = f16((v-hi)*4096)  (scaled to stay f16-normal)
__global__ void desc_split_kernel(const float* __restrict__ x, const float* __restrict__ invn,
                                  _Float16* __restrict__ hi, _Float16* __restrict__ lo,
                                  int C, int H, int W, int total) {
  int i = blockIdx.x * blockDim.x + threadIdx.x;
  if (i >= total) return;
  int c = i % C;
  int p = (i / C) % (H * W);
  int b = i / (C * H * W);
  int ph = p / W, pw = p % W;
  float s = invn[b * H * W + p];
  size_t obase = ((size_t)b * H * W + p) * (size_t)(C * 9) + (size_t)c * 9;
  const float* xb = x + (size_t)(b * C + c) * H * W;
#pragma unroll
  for (int r = 0; r < 9; ++r) {
    int y = ph + r / 3 - 1, xx = pw + r % 3 - 1;
    float v = 0.f;
    if (y >= 0 && y < H && xx >= 0 && xx < W) v = xb[y * W + xx] * s;
    _Float16 h = (_Float16)v;
    float hf = (float)h;
    _Float16 l = (_Float16)((v - hf) * 4096.0f);
    hi[obase + r] = h;
    lo[obase + r] = l;
  }
}

// Axis-2 (m / column) bicubic upsample: out[b][n][mo], mo in [0, Mout)
// (bicubic is separable; doing the m-pass first commutes exactly with the
//  n-pass done in the mfma epilogue, clamps included)
__global__ void upsample_m_kernel(const float* __restrict__ Rin, float* __restrict__ out,
                                  int Nrows, int Min, float invscale, int Mout, int total) {
  int i = blockIdx.x * blockDim.x + threadIdx.x;
  if (i >= total) return;
  int mo = i % Mout;
  int n = (i / Mout) % Nrows;
  int b = i / (Mout * Nrows);
  float src = (mo + 0.5f) * invscale - 0.5f;
  float f = floorf(src);
  float tt = src - f;
  int fi = (int)f;
  const float* Rb = Rin + ((size_t)b * Nrows + n) * Min;
  float s = 0.f;
#pragma unroll
  for (int tp = 0; tp < 4; ++tp) {
    int ii = min(max(fi + tp - 1, 0), Min - 1);
    s += cubicw(tt - (float)(tp - 1)) * Rb[ii];
  }
  out[i] = s;
}

__global__ void init_packed_kernel(unsigned long long* __restrict__ p, int n) {
  int i = blockIdx.x * blockDim.x + threadIdx.x;
  if (i < n) p[i] = 0ull;
}

// 64x64-tile fp32 GEMM (4x4 microtile), register-prefetch pipelined. R2.
__global__ __launch_bounds__(256)
void gemm64_kernel(const float* __restrict__ A, const float* __restrict__ B,
                   float* __restrict__ C, int M, int N, int K) {
  int b = blockIdx.z;
  const float* Ab = A + (size_t)b * M * K;
  const float* Bb = B + (size_t)b * K * N;
  __shared__ float As[16][68];
  __shared__ float Bs[16][64];
  int row0 = blockIdx.y * 64;
  int col0 = blockIdx.x * 64;
  int t = threadIdx.x;
  int tx = t & 15, ty = t >> 4;
  float acc[4][4] = {};
  int la_r = t >> 2;
  int la_k = (t & 3) << 2;
  int lb_r = t >> 4;
  int lb_c = (t & 15) << 2;
  const float* Aptr = Ab + (size_t)(row0 + la_r) * K + la_k;
  const float* Bptr = Bb + (size_t)lb_r * N + col0 + lb_c;
  float4 av = *(const float4*)(Aptr);
  float4 bv = *(const float4*)(Bptr);
  for (int k0 = 0; k0 < K; k0 += 16) {
    __syncthreads();
    As[la_k + 0][la_r] = av.x;
    As[la_k + 1][la_r] = av.y;
    As[la_k + 2][la_r] = av.z;
    As[la_k + 3][la_r] = av.w;
    *(float4*)&Bs[lb_r][lb_c] = bv;
    __syncthreads();
    if (k0 + 16 < K) {
      av = *(const float4*)(Aptr + k0 + 16);
      bv = *(const float4*)(Bptr + (size_t)(k0 + 16) * N);
    }
#pragma unroll
    for (int k = 0; k < 16; ++k) {
      float4 a = *(const float4*)&As[k][ty << 2];
      float4 bq = *(const float4*)&Bs[k][tx << 2];
      float av4[4] = {a.x, a.y, a.z, a.w};
      float bv4[4] = {bq.x, bq.y, bq.z, bq.w};
#pragma unroll
      for (int ii = 0; ii < 4; ++ii)
#pragma unroll
        for (int jj = 0; jj < 4; ++jj)
          acc[ii][jj] = fmaf(av4[ii], bv4[jj], acc[ii][jj]);
    }
  }
  float* Cb = C + (size_t)b * M * N;
#pragma unroll
  for (int ii = 0; ii < 4; ++ii) {
    float4 v = make_float4(acc[ii][0], acc[ii][1], acc[ii][2], acc[ii][3]);
    *(float4*)&Cb[(size_t)(row0 + (ty << 2) + ii) * N + col0 + (tx << 2)] = v;
  }
}

// Split-K variant with atomicAdd epilogue (for the tiny R1 GEMM: 32 blocks
// would leave 87% of the CUs idle; SK=8 -> 256 blocks). C must be zeroed.
__global__ __launch_bounds__(256)
void gemm64sk_kernel(const float* __restrict__ A, const float* __restrict__ B,
                     float* __restrict__ C, int M, int N, int K, int SK) {
  int zz = blockIdx.z;
  int b = zz / SK, kc = zz % SK;
  int kchunk = K / SK;                    // must be a multiple of 16
  int kbeg = kc * kchunk, kend = kbeg + kchunk;
  const float* Ab = A + (size_t)b * M * K;
  const float* Bb = B + (size_t)b * K * N;
  __shared__ float As[16][68];
  __shared__ float Bs[16][64];
  int row0 = blockIdx.y * 64;
  int col0 = blockIdx.x * 64;
  int t = threadIdx.x;
  int tx = t & 15, ty = t >> 4;
  float acc[4][4] = {};
  int la_r = t >> 2;
  int la_k = (t & 3) << 2;
  int lb_r = t >> 4;
  int lb_c = (t & 15) << 2;
  const float* Aptr = Ab + (size_t)(row0 + la_r) * K + la_k;
  const float* Bptr = Bb + (size_t)lb_r * N + col0 + lb_c;
  float4 av = *(const float4*)(Aptr + kbeg);
  float4 bv = *(const float4*)(Bptr + (size_t)kbeg * N);
  for (int k0 = kbeg; k0 < kend; k0 += 16) {
    __syncthreads();
    As[la_k + 0][la_r] = av.x;
    As[la_k + 1][la_r] = av.y;
    As[la_k + 2][la_r] = av.z;
    As[la_k + 3][la_r] = av.w;
    *(float4*)&Bs[lb_r][lb_c] = bv;
    __syncthreads();
    if (k0 + 16 < kend) {
      av = *(const float4*)(Aptr + k0 + 16);
      bv = *(const float4*)(Bptr + (size_t)(k0 + 16) * N);
    }
#pragma unroll
    for (int k = 0; k < 16; ++k) {
      float4 a = *(const float4*)&As[k][ty << 2];
      float4 bq = *(const float4*)&Bs[k][tx << 2];
      float av4[4] = {a.x, a.y, a.z, a.w};
      float bv4[4] = {bq.x, bq.y, bq.z, bq.w};
#pragma unroll
      for (int ii = 0; ii < 4; ++ii)
#pragma unroll
        for (int jj = 0; jj < 4; ++jj)
          acc[ii][jj] = fmaf(av4[ii], bv4[jj], acc[ii][jj]);
    }
  }
  float* Cb = C + (size_t)b * M * N;
#pragma unroll
  for (int ii = 0; ii < 4; ++ii)
#pragma unroll
    for (int jj = 0; jj < 4; ++jj)
      atomicAdd(&Cb[(size_t)(row0 + (ty << 2) + ii) * N + col0 + (tx << 2) + jj],
                acc[ii][jj]);
}

// MFMA split-f16 GEMM, 128x128 workgroup tile, wave=64x64 (4x4 of 16x16x32),
// fused bicubic-tap add + /3 + packed max/argmax over the ref axis (rows).
//
// Main loop = R1's proven ordering: ds_read(buf) FIRST, then issue next tile's
// DMA into buf^1, then MFMA, then barrier. (R2's issue-before-ds_read forced a
// conservative vmcnt drain ahead of the ds_reads -> serialized the pipeline and
// collapsed L2 locality: 628us, 878MB fetch. Reverted.)
// Epilogue = LDS-staged n-taps on the m-pre-upsampled up2m/up1m slices
// (24KB/block coalesced staging instead of ~1GB of scattered 4B L2 reads).
__global__ __launch_bounds__(256, 2)
void mfma_fused_kernel(const _Float16* __restrict__ Ahi, const _Float16* __restrict__ Alo,
                       const _Float16* __restrict__ Bhi, const _Float16* __restrict__ Blo,
                       const float* __restrict__ up2m, const float* __restrict__ up1m,
                       unsigned long long* __restrict__ packed) {
  const int K = 576;
  // ---- XCD swizzle: grid is (32,32,2) = 2048 blocks; 2048 % 8 == 0 -> bijective
  int bid = (blockIdx.z * 32 + blockIdx.y) * 32 + blockIdx.x;
  int swz = (bid & 7) * 256 + (bid >> 3);
  int bx = swz & 31;
  int by = (swz >> 5) & 31;
  int b  = swz >> 10;

  int row0 = by * 128;   // ref axis (n) — argmax axis
  int col0 = bx * 128;   // lr axis (m) — output positions
  int t = threadIdx.x;
  int lane = t & 63, wave = t >> 6;
  int wy = wave & 1, wx = wave >> 1;
  int quad = lane >> 4, lm = lane & 15;

  // LDS: [buf:2][plane:4][8KB tile]. plane 0=AH 1=AL 2=BH 3=BL.
  __shared__ _Float16 lds[2 * 4 * 4096];

  // ---- staging source offsets (per-lane, bytes into a [128][K] half-plane).
  // Linear dest chunk d = wave*128 + h*64 + lane; invert the chunk swizzle
  // (chunk3 ^= line&7) to find which (row, col16) to fetch into that slot.
  int off[2];
#pragma unroll
  for (int h = 0; h < 2; ++h) {
    int d = wave * 128 + h * 64 + lane;
    int line = d >> 3;
    int c3 = (d & 7) ^ (line & 7);
    int row = (line << 1) | (c3 >> 2);
    int c = c3 & 3;
    off[h] = row * (K * 2) + c * 16;
  }
  const char* pg[4];
  pg[0] = (const char*)Ahi + ((size_t)b * 4096 + row0) * (size_t)K * 2;
  pg[1] = (const char*)Alo + ((size_t)b * 4096 + row0) * (size_t)K * 2;
  pg[2] = (const char*)Bhi + ((size_t)b * 4096 + col0) * (size_t)K * 2;
  pg[3] = (const char*)Blo + ((size_t)b * 4096 + col0) * (size_t)K * 2;

  // ---- fragment ds_read addresses (bytes into an 8KB plane), swizzled.
  int ra[4], rb[4];
#pragma unroll
  for (int i = 0; i < 4; ++i) {
    int rowa = wy * 64 + i * 16 + lm;
    int la_ = rowa >> 1;
    ra[i] = la_ * 128 + (((((rowa & 1) << 2) | quad) ^ (la_ & 7)) << 4);
    int rowb = wx * 64 + i * 16 + lm;
    int lb_ = rowb >> 1;
    rb[i] = lb_ * 128 + (((((rowb & 1) << 2) | quad) ^ (lb_ & 7)) << 4);
  }

  f32x4 S1[4][4] = {};
  f32x4 S2[4][4] = {};

  // stage tile 0 into buf 0
#pragma unroll
  for (int p = 0; p < 4; ++p) {
    char* lw = (char*)lds + p * 8192 + wave * 2048;
    gload_lds16(pg[p] + off[0], lw);
    gload_lds16(pg[p] + off[1], lw + 1024);
  }
  __syncthreads();

  int buf = 0;
  for (int t18 = 0; t18 < 18; ++t18) {
    const char* lb = (const char*)lds + buf * 32768;
    half8 aH[4], aL[4], bH[4], bL[4];
#pragma unroll
    for (int i = 0; i < 4; ++i) {
      aH[i] = *(const half8*)(lb + ra[i]);
      aL[i] = *(const half8*)(lb + 8192 + ra[i]);
      bH[i] = *(const half8*)(lb + 16384 + rb[i]);
      bL[i] = *(const half8*)(lb + 24576 + rb[i]);
    }
    // prefetch next tile into the other buffer; flies under the MFMA phase,
    // drained by the vmcnt(0) the compiler emits at the trailing barrier.
    if (t18 < 17) {
      int kbyte = (t18 + 1) * 64;
#pragma unroll
      for (int p = 0; p < 4; ++p) {
        char* lw = (char*)lds + (buf ^ 1) * 32768 + p * 8192 + wave * 2048;
        gload_lds16(pg[p] + kbyte + off[0], lw);
        gload_lds16(pg[p] + kbyte + off[1], lw + 1024);
      }
    }
#pragma unroll
    for (int i = 0; i < 4; ++i)
#pragma unroll
      for (int j = 0; j < 4; ++j) {
        S1[i][j] = __builtin_amdgcn_mfma_f32_16x16x32_f16(aH[i], bH[j], S1[i][j], 0, 0, 0);
        S2[i][j] = __builtin_amdgcn_mfma_f32_16x16x32_f16(aH[i], bL[j], S2[i][j], 0, 0, 0);
        S2[i][j] = __builtin_amdgcn_mfma_f32_16x16x32_f16(aL[i], bH[j], S2[i][j], 0, 0, 0);
      }
    __syncthreads();
    buf ^= 1;
  }

  // ---- epilogue: stage n-tap slices of up2m/up1m into LDS, then
  //      v = S1 + S2*2^-12 + n-bicubic(up2m) + n-bicubic(up1m); /3; max/argmax.
  // (main loop ended with a barrier; LDS is free to reuse)
  float* up2s = (float*)lds;                 // [36][132]
  float* up1s = (float*)lds + 36 * 132;      // [12][132]
  int base2 = (row0 >> 2) - 2;               // up2m row window [base2, base2+35]
  int base1 = (row0 >> 4) - 2;               // up1m row window [base1, base1+11]
  {
    const float* u2 = up2m + (size_t)b * 1024 * 4096;
    const float* u1 = up1m + (size_t)b * 256 * 4096;
    for (int idx = t; idx < 36 * 128; idx += 256) {
      int rr = idx >> 7, cc = idx & 127;
      int gr = min(max(base2 + rr, 0), 1023);
      up2s[rr * 132 + cc] = u2[(size_t)gr * 4096 + col0 + cc];
    }
    for (int idx = t; idx < 12 * 128; idx += 256) {
      int rr = idx >> 7, cc = idx & 127;
      int gr = min(max(base1 + rr, 0), 255);
      up1s[rr * 132 + cc] = u1[(size_t)gr * 4096 + col0 + cc];
    }
  }
  __syncthreads();

  const float inv4096 = 1.0f / 4096.0f;
  unsigned long long best[4] = {0ull, 0ull, 0ull, 0ull};
#pragma unroll
  for (int i = 0; i < 4; ++i) {
#pragma unroll
    for (int r = 0; r < 4; ++r) {
      int gn = row0 + wy * 64 + i * 16 + quad * 4 + r;
      float s2 = (gn + 0.5f) * 0.25f - 0.5f;
      float f2 = floorf(s2); float t2 = s2 - f2; int i2 = (int)f2;
      int sl2 = i2 - 1 - base2;              // 0..32
      float w2[4];
      float s1 = (gn + 0.5f) * 0.0625f - 0.5f;
      float f1 = floorf(s1); float t1 = s1 - f1; int i1 = (int)f1;
      int sl1 = i1 - 1 - base1;              // 0..8
      float w1[4];
#pragma unroll
      for (int tp = 0; tp < 4; ++tp) {
        w2[tp] = cubicw(t2 - (float)(tp - 1));
        w1[tp] = cubicw(t1 - (float)(tp - 1));
      }
      const float* p2 = up2s + sl2 * 132;
      const float* p1 = up1s + sl1 * 132;
#pragma unroll
      for (int j = 0; j < 4; ++j) {
        int gml = wx * 64 + j * 16 + lm;
        float u = w2[0] * p2[gml]       + w2[1] * p2[132 + gml]
                + w2[2] * p2[264 + gml] + w2[3] * p2[396 + gml]
                + w1[0] * p1[gml]       + w1[1] * p1[132 + gml]
                + w1[2] * p1[264 + gml] + w1[3] * p1[396 + gml];
        float v = (S1[i][j][r] + S2[i][j][r] * inv4096 + u) * (1.0f / 3.0f);
        unsigned int fb = __float_as_uint(v);
        unsigned int key = (fb & 0x80000000u) ? ~fb : (fb | 0x80000000u);
        unsigned long long pk = ((unsigned long long)key << 32)
                              | (unsigned long long)(0xFFFFFFFFu - (unsigned)gn);
        best[j] = best[j] > pk ? best[j] : pk;
      }
    }
  }
#pragma unroll
  for (int j = 0; j < 4; ++j) {
    unsigned long long bb = best[j];
    unsigned long long o;
    o = __shfl_xor(bb, 16); bb = bb > o ? bb : o;
    o = __shfl_xor(bb, 32); bb = bb > o ? bb : o;
    if (lane < 16) {
      int gm = col0 + wx * 64 + j * 16 + lm;
      atomicMax(&packed[(size_t)b * 4096 + gm], bb);
    }
  }
}

__global__ void finalize_kernel(const unsigned long long* __restrict__ packed,
                                float* __restrict__ s3_out, int* __restrict__ arg, int total) {
  int i = blockIdx.x * blockDim.x + threadIdx.x;
  if (i >= total) return;
  unsigned long long pk = packed[i];
  unsigned int key = (unsigned int)(pk >> 32);
  unsigned int fb = (key & 0x80000000u) ? (key ^ 0x80000000u) : ~key;
  s3_out[i] = __uint_as_float(fb);
  arg[i] = (int)(0xFFFFFFFFu - (unsigned int)(pk & 0xFFFFFFFFull));
}

// Batched 2D transpose: out[b][s][r] = in[b][r][s].  R, S multiples of 32.
__global__ __launch_bounds__(256)
void transpose_kernel(const float* __restrict__ in, float* __restrict__ out,
                      int R, int S) {
  __shared__ float tile[32][33];
  int b = blockIdx.z;
  int s0 = blockIdx.x * 32, r0 = blockIdx.y * 32;
  int tx = threadIdx.x & 31, ty = threadIdx.x >> 5;   // ty in 0..7
  const float* ib = in + (size_t)b * R * S;
  float* ob = out + (size_t)b * R * S;
#pragma unroll
  for (int k = 0; k < 4; ++k)
    tile[ty + 8 * k][tx] = ib[(size_t)(r0 + ty + 8 * k) * S + s0 + tx];
  __syncthreads();
#pragma unroll
  for (int k = 0; k < 4; ++k)
    ob[(size_t)(s0 + ty + 8 * k) * R + r0 + tx] = tile[tx][ty + 8 * k];
}

// Channel-last fold-gather: lanes map to c (fastest dim) so every tap is a
// contiguous C*4B read from refT [b][h][w][c]; writes TT [b][h][w][c].
template<int KK, int SS, int PP, int CL2, int WL2>
__global__ void fold_gather_cl_kernel(const float* __restrict__ refT,
                                      const int* __restrict__ arg,
                                      float* __restrict__ TT, int total) {
  const int C = 1 << CL2, W = 1 << WL2;
  int i = blockIdx.x * blockDim.x + threadIdx.x;
  if (i >= total) return;
  int c = i & (C - 1);
  int p = i >> CL2;                 // p = (b*H + h)*W + w   (H == W)
  int w = p & (W - 1);
  int h = (p >> WL2) & (W - 1);
  int b = p >> (2 * WL2);
  int y = h + PP, x = w + PP;
  int ho_lo = (y - KK + 1) > 0 ? (y - KK + 1 + SS - 1) / SS : 0;
  int ho_hi = min(63, y / SS);
  int wo_lo = (x - KK + 1) > 0 ? (x - KK + 1 + SS - 1) / SS : 0;
  int wo_hi = min(63, x / SS);
  const int* argb = arg + b * 4096;
  const float* refb = refT + ((size_t)b << (2 * WL2 + CL2));
  float acc = 0.f;
  for (int ho = ho_lo; ho <= ho_hi; ++ho) {
    int ki = y - SS * ho;
    for (int wo = wo_lo; wo <= wo_hi; ++wo) {
      int kj = x - SS * wo;
      int q = argb[(ho << 6) + wo];
      int qh = q >> 6, qw = q & 63;
      int ry = SS * qh + ki - PP;
      int rx = SS * qw + kj - PP;
      if (ry >= 0 && ry < W && rx >= 0 && rx < W)
        acc += refb[(((size_t)ry << WL2) + rx << CL2) + c];
    }
  }
  TT[(size_t)p * C + c] = acc * (1.0f / 9.0f);
}

extern "C" void kernel_launch(void* const* d_in, const int* in_sizes, int n_in,
                              void* d_out, int out_size, void* d_ws, size_t ws_size,
                              hipStream_t stream) {
  const float* lrsr1 = (const float*)d_in[0];
  const float* lrsr2 = (const float*)d_in[1];
  const float* lrsr3 = (const float*)d_in[2];
  const float* refsr1 = (const float*)d_in[3];
  const float* refsr2 = (const float*)d_in[4];
  const float* refsr3 = (const float*)d_in[5];
  const float* ref1 = (const float*)d_in[6];
  const float* ref2 = (const float*)d_in[7];
  const float* ref3 = (const float*)d_in[8];
  float* out = (float*)d_out;
  float* ws = (float*)d_ws;

  const int B = 2;
  // level-3 f16 planes occupy the first region: 4 planes x [2][4096][576] halves
  size_t off_planes = 0;
  size_t off_r2n = off_planes + (size_t)B * 4096 * 576 * 2; // floats (= 4 half-planes)
  size_t off_l2n = off_r2n + (size_t)B * 1024 * 1152;   // [2,1152,1024]
  size_t off_r1n = off_l2n + (size_t)B * 1152 * 1024;   // [2,256,2304]
  size_t off_l1n = off_r1n + (size_t)B * 256 * 2304;    // [2,2304,256]
  size_t off_R2  = off_l1n + (size_t)B * 2304 * 256;    // [2,1024,1024]
  size_t off_R1  = off_R2  + (size_t)B * 1024 * 1024;   // [2,256,256]
  size_t off_up2 = off_R1  + (size_t)B * 256 * 256;     // [2,1024,4096] (m-upsampled)
  size_t off_up1 = off_up2 + (size_t)B * 1024 * 4096;   // [2,256,4096]
  size_t off_S   = off_up1 + (size_t)B * 256 * 4096;    // [2,4096]
  size_t off_invn= off_S   + (size_t)B * 4096;          // [2,4096]
  size_t off_pk  = off_invn+ (size_t)B * 4096;          // [2,4096] u64
  size_t off_arg = off_pk  + (size_t)B * 4096 * 2;      // [2,4096] int

  const size_t PLANE = (size_t)B * 4096 * 576;          // halves per plane
  _Float16* r3hi = (_Float16*)(ws + off_planes);
  _Float16* r3lo = r3hi + PLANE;
  _Float16* l3hi = r3lo + PLANE;
  _Float16* l3lo = l3hi + PLANE;

  auto run_desc32 = [&](const float* x, int C, int H, int W, float* outbuf, bool r_layout) {
    int HW = H * W;
    int tS = B * HW;
    sumsq_kernel<<<DIVUP(tS, 256), 256, 0, stream>>>(x, ws + off_S, C, HW, tS);
    invnorm_kernel<<<DIVUP(tS, 256), 256, 0, stream>>>(ws + off_S, ws + off_invn, H, W, tS);
    int tD = B * C * 9 * HW;
    if (r_layout)
      desc_r_kernel<<<DIVUP(tD, 256), 256, 0, stream>>>(x, ws + off_invn, outbuf, C, H, W, tD);
    else
      desc_l_kernel<<<DIVUP(tD, 256), 256, 0, stream>>>(x, ws + off_invn, outbuf, C, H, W, tD);
  };
  auto run_desc_split = [&](const float* x, _Float16* hi, _Float16* lo) {
    int C = 64, H = 64, W = 64, HW = H * W;
    int tS = B * HW;
    sumsq_kernel<<<DIVUP(tS, 256), 256, 0, stream>>>(x, ws + off_S, C, HW, tS);
    invnorm_kernel<<<DIVUP(tS, 256), 256, 0, stream>>>(ws + off_S, ws + off_invn, H, W, tS);
    int tD = B * C * HW;
    desc_split_kernel<<<DIVUP(tD, 256), 256, 0, stream>>>(x, ws + off_invn, hi, lo, C, H, W, tD);
  };

  // level 3 split-f16 descriptors (both pixel-major [4096][576])
  run_desc_split(refsr3, r3hi, r3lo);
  run_desc_split(lrsr3, l3hi, l3lo);
  // levels 1/2 fp32 descriptors
  run_desc32(lrsr2, 128, 32, 32, ws + off_l2n, false);
  run_desc32(refsr2, 128, 32, 32, ws + off_r2n, true);
  run_desc32(lrsr1, 256, 16, 16, ws + off_l1n, false);
  run_desc32(refsr1, 256, 16, 16, ws + off_r1n, true);

  // small correlation GEMMs R2 (plain), R1 (split-K x8, 256 blocks)
  {
    dim3 g(1024 / 64, 1024 / 64, B);
    gemm64_kernel<<<g, 256, 0, stream>>>(ws + off_r2n, ws + off_l2n, ws + off_R2,
                                         1024, 1024, 1152);
  }
  {
    init_packed_kernel<<<DIVUP(65536, 256), 256, 0, stream>>>(
        (unsigned long long*)(ws + off_R1), 65536);   // zero R1 (2*256*256 f32)
    dim3 g(256 / 64, 256 / 64, B * 8);
    gemm64sk_kernel<<<g, 256, 0, stream>>>(ws + off_r1n, ws + off_l1n, ws + off_R1,
                                           256, 256, 2304, 8);
  }

  // axis-2 (m) bicubic upsample of R2 (x4) and R1 (x16) to 4096 cols
  {
    int tU2 = B * 1024 * 4096;
    upsample_m_kernel<<<DIVUP(tU2, 256), 256, 0, stream>>>(ws + off_R2, ws + off_up2,
                                                           1024, 1024, 0.25f, 4096, tU2);
    int tU1 = B * 256 * 4096;
    upsample_m_kernel<<<DIVUP(tU1, 256), 256, 0, stream>>>(ws + off_R1, ws + off_up1,
                                                           256, 256, 0.0625f, 4096, tU1);
  }

  unsigned long long* pk = (unsigned long long*)(ws + off_pk);
  init_packed_kernel<<<DIVUP(B * 4096, 256), 256, 0, stream>>>(pk, B * 4096);

  // fused R3 MFMA GEMM + bicubic add + max/argmax
  {
    dim3 g(4096 / 128, 4096 / 128, B);
    mfma_fused_kernel<<<g, 256, 0, stream>>>(r3hi, r3lo, l3hi, l3lo,
                                             ws + off_up2, ws + off_up1, pk);
  }

  int* argp = (int*)(ws + off_arg);
  finalize_kernel<<<DIVUP(B * 4096, 256), 256, 0, stream>>>(pk, out, argp, B * 4096);

  // transfer: fold(gather(unfold(ref_lvX)))/9 — channel-last pipeline.
  // Dead regions reused: refT at ws+0 (planes region, 9.44M floats),
  // TT at ws+off_up2 (8.39M floats).
  float* refT = ws + off_planes;
  float* TT = ws + off_up2;
  float* T3 = out + 8192;
  float* T2 = T3 + (size_t)B * 256 * 64 * 64;
  float* T1 = T2 + (size_t)B * 128 * 128 * 128;
  // ---- T3: C=256, P=4096 (64x64)
  {
    dim3 g1(4096 / 32, 256 / 32, B);
    transpose_kernel<<<g1, 256, 0, stream>>>(ref3, refT, 256, 4096);
    int tt = B * 4096 * 256;
    fold_gather_cl_kernel<3, 1, 1, 8, 6><<<DIVUP(tt, 256), 256, 0, stream>>>(refT, argp, TT, tt);
    dim3 g2(256 / 32, 4096 / 32, B);
    transpose_kernel<<<g2, 256, 0, stream>>>(TT, T3, 4096, 256);
  }
  // ---- T2: C=128, P=16384 (128x128)
  {
    dim3 g1(16384 / 32, 128 / 32, B);
    transpose_kernel<<<g1, 256, 0, stream>>>(ref2, refT, 128, 16384);
    int tt = B * 16384 * 128;
    fold_gather_cl_kernel<6, 2, 2, 7, 7><<<DIVUP(tt, 256), 256, 0, stream>>>(refT, argp, TT, tt);
    dim3 g2(128 / 32, 16384 / 32, B);
    transpose_kernel<<<g2, 256, 0, stream>>>(TT, T2, 16384, 128);
  }
  // ---- T1: C=64, P=65536 (256x256)
  {
    dim3 g1(65536 / 32, 64 / 32, B);
    transpose_kernel<<<g1, 256, 0, stream>>>(ref1, refT, 64, 65536);
    int tt = B * 65536 * 64;
    fold_gather_cl_kernel<12, 4, 4, 6, 8><<<DIVUP(tt, 256), 256, 0, stream>>>(refT, argp, TT, tt);
    dim3 g2(64 / 32, 65536 / 32, B);
    transpose_kernel<<<g2, 256, 0, stream>>>(TT, T1, 65536, 64);
  }
}

// Round 4
// 1113.849 us; speedup vs baseline: 1.3788x; 1.3788x over previous
//
#include <hip/hip_runtime.h>
#include <cstdint>

#define DIVUP(a,b) (((a)+(b)-1)/(b))

typedef __attribute__((ext_vector_type(4))) float f32x4;
typedef __attribute__((ext_vector_type(8))) _Float16 half8;

// Direct global->LDS DMA, 16B per lane. LDS dest is WAVE-UNIFORM base + lane*16.
__device__ __forceinline__ void gload_lds16(const void* g, void* l) {
  __builtin_amdgcn_global_load_lds(
      (const __attribute__((address_space(1))) void*)g,
      (__attribute__((address_space(3))) void*)l, 16, 0, 0);
}

__device__ __forceinline__ float cubicw(float x) {
  // PyTorch bicubic kernel, a = -0.75
  float ax = fabsf(x);
  float ax2 = ax * ax;
  float ax3 = ax2 * ax;
  if (ax <= 1.0f) return 1.25f * ax3 - 2.25f * ax2 + 1.0f;
  if (ax < 2.0f)  return -0.75f * ax3 + 3.75f * ax2 - 6.0f * ax + 3.0f;
  return 0.0f;
}

// S[b,pix] = sum_c x[b,c,pix]^2
__global__ void sumsq_kernel(const float* __restrict__ x, float* __restrict__ S,
                             int C, int HW, int total) {
  int i = blockIdx.x * blockDim.x + threadIdx.x;
  if (i >= total) return;
  int pix = i % HW, b = i / HW;
  const float* p = x + (size_t)b * C * HW + pix;
  float s = 0.f;
  for (int c = 0; c < C; ++c) { float v = p[(size_t)c * HW]; s += v * v; }
  S[i] = s;
}

// invn[b,p] = 1 / max(sqrt(3x3 zero-padded window sum of S), 1e-12)
__global__ void invnorm_kernel(const float* __restrict__ S, float* __restrict__ invn,
                               int H, int W, int total) {
  int i = blockIdx.x * blockDim.x + threadIdx.x;
  if (i >= total) return;
  int p = i % (H * W), b = i / (H * W);
  int ph = p / W, pw = p % W;
  const float* Sb = S + (size_t)b * H * W;
  float s = 0.f;
  for (int ki = 0; ki < 3; ++ki) {
    int y = ph + ki - 1;
    if (y < 0 || y >= H) continue;
    for (int kj = 0; kj < 3; ++kj) {
      int xx = pw + kj - 1;
      if (xx < 0 || xx >= W) continue;
      s += Sb[y * W + xx];
    }
  }
  float n = fmaxf(sqrtf(s), 1e-12f);
  invn[i] = 1.0f / n;
}

// l-layout descriptors (fp32, D-major) for levels 1/2
__global__ void desc_l_kernel(const float* __restrict__ x, const float* __restrict__ invn,
                              float* __restrict__ out, int C, int H, int W, int total) {
  int i = blockIdx.x * blockDim.x + threadIdx.x;
  if (i >= total) return;
  int HW = H * W, D = C * 9;
  int p = i % HW;
  int d = (i / HW) % D;
  int b = i / (HW * D);
  int c = d / 9, r = d % 9, ki = r / 3, kj = r % 3;
  int ph = p / W, pw = p % W;
  int y = ph + ki - 1, xx = pw + kj - 1;
  float v = 0.f;
  if (y >= 0 && y < H && xx >= 0 && xx < W) v = x[((size_t)(b * C + c) * H + y) * W + xx];
  out[i] = v * invn[b * HW + p];
}

// r-layout descriptors (fp32, N-major) for levels 1/2
__global__ void desc_r_kernel(const float* __restrict__ x, const float* __restrict__ invn,
                              float* __restrict__ out, int C, int H, int W, int total) {
  int i = blockIdx.x * blockDim.x + threadIdx.x;
  if (i >= total) return;
  int HW = H * W, D = C * 9;
  int d = i % D;
  int p = (i / D) % HW;
  int b = i / (D * HW);
  int c = d / 9, r = d % 9, ki = r / 3, kj = r % 3;
  int ph = p / W, pw = p % W;
  int y = ph + ki - 1, xx = pw + kj - 1;
  float v = 0.f;
  if (y >= 0 && y < H && xx >= 0 && xx < W) v = x[((size_t)(b * C + c) * H + y) * W + xx];
  out[i] = v * invn[b * HW + p];
}

// Level-3 split-f16 descriptors, pixel-major [B][4096][576]:
// hi = f16(v), lo = f16((v-hi)*4096)  (scaled to stay f16-normal)
__global__ void desc_split_kernel(const float* __restrict__ x, const float* __restrict__ invn,
                                  _Float16* __restrict__ hi, _Float16* __restrict__ lo,
                                  int C, int H, int W, int total) {
  int i = blockIdx.x * blockDim.x + threadIdx.x;
  if (i >= total) return;
  int c = i % C;
  int p = (i / C) % (H * W);
  int b = i / (C * H * W);
  int ph = p / W, pw = p % W;
  float s = invn[b * H * W + p];
  size_t obase = ((size_t)b * H * W + p) * (size_t)(C * 9) + (size_t)c * 9;
  const float* xb = x + (size_t)(b * C + c) * H * W;
#pragma unroll
  for (int r = 0; r < 9; ++r) {
    int y = ph + r / 3 - 1, xx = pw + r % 3 - 1;
    float v = 0.f;
    if (y >= 0 && y < H && xx >= 0 && xx < W) v = xb[y * W + xx] * s;
    _Float16 h = (_Float16)v;
    float hf = (float)h;
    _Float16 l = (_Float16)((v - hf) * 4096.0f);
    hi[obase + r] = h;
    lo[obase + r] = l;
  }
}

// Axis-1 bicubic upsample to 4096 rows (R1-proven layout: out [b][4096][cols])
__global__ void upsample_n_kernel(const float* __restrict__ Rin, float* __restrict__ out,
                                  int Nin, int cols, float invscale, int total) {
  int i = blockIdx.x * blockDim.x + threadIdx.x;
  if (i >= total) return;
  int j = i % cols;
  int n = (i / cols) & 4095;
  int b = i / (cols * 4096);
  float src = (n + 0.5f) * invscale - 0.5f;
  float f = floorf(src);
  float tt = src - f;
  int fi = (int)f;
  const float* Rb = Rin + (size_t)b * Nin * cols;
  float s = 0.f;
#pragma unroll
  for (int tp = 0; tp < 4; ++tp) {
    int ii = min(max(fi + tp - 1, 0), Nin - 1);
    s += cubicw(tt - (float)(tp - 1)) * Rb[(size_t)ii * cols + j];
  }
  out[i] = s;
}

__global__ void init_packed_kernel(unsigned long long* __restrict__ p, int n) {
  int i = blockIdx.x * blockDim.x + threadIdx.x;
  if (i < n) p[i] = 0ull;
}

// 64x64-tile fp32 GEMM (4x4 microtile), register-prefetch pipelined. R2.
__global__ __launch_bounds__(256)
void gemm64_kernel(const float* __restrict__ A, const float* __restrict__ B,
                   float* __restrict__ C, int M, int N, int K) {
  int b = blockIdx.z;
  const float* Ab = A + (size_t)b * M * K;
  const float* Bb = B + (size_t)b * K * N;
  __shared__ float As[16][68];
  __shared__ float Bs[16][64];
  int row0 = blockIdx.y * 64;
  int col0 = blockIdx.x * 64;
  int t = threadIdx.x;
  int tx = t & 15, ty = t >> 4;
  float acc[4][4] = {};
  int la_r = t >> 2;
  int la_k = (t & 3) << 2;
  int lb_r = t >> 4;
  int lb_c = (t & 15) << 2;
  const float* Aptr = Ab + (size_t)(row0 + la_r) * K + la_k;
  const float* Bptr = Bb + (size_t)lb_r * N + col0 + lb_c;
  float4 av = *(const float4*)(Aptr);
  float4 bv = *(const float4*)(Bptr);
  for (int k0 = 0; k0 < K; k0 += 16) {
    __syncthreads();
    As[la_k + 0][la_r] = av.x;
    As[la_k + 1][la_r] = av.y;
    As[la_k + 2][la_r] = av.z;
    As[la_k + 3][la_r] = av.w;
    *(float4*)&Bs[lb_r][lb_c] = bv;
    __syncthreads();
    if (k0 + 16 < K) {
      av = *(const float4*)(Aptr + k0 + 16);
      bv = *(const float4*)(Bptr + (size_t)(k0 + 16) * N);
    }
#pragma unroll
    for (int k = 0; k < 16; ++k) {
      float4 a = *(const float4*)&As[k][ty << 2];
      float4 bq = *(const float4*)&Bs[k][tx << 2];
      float av4[4] = {a.x, a.y, a.z, a.w};
      float bv4[4] = {bq.x, bq.y, bq.z, bq.w};
#pragma unroll
      for (int ii = 0; ii < 4; ++ii)
#pragma unroll
        for (int jj = 0; jj < 4; ++jj)
          acc[ii][jj] = fmaf(av4[ii], bv4[jj], acc[ii][jj]);
    }
  }
  float* Cb = C + (size_t)b * M * N;
#pragma unroll
  for (int ii = 0; ii < 4; ++ii) {
    float4 v = make_float4(acc[ii][0], acc[ii][1], acc[ii][2], acc[ii][3]);
    *(float4*)&Cb[(size_t)(row0 + (ty << 2) + ii) * N + col0 + (tx << 2)] = v;
  }
}

// Split-K variant with atomicAdd epilogue (for the tiny R1 GEMM: 32 blocks
// would leave 87% of the CUs idle; SK=8 -> 256 blocks). C must be zeroed.
__global__ __launch_bounds__(256)
void gemm64sk_kernel(const float* __restrict__ A, const float* __restrict__ B,
                     float* __restrict__ C, int M, int N, int K, int SK) {
  int zz = blockIdx.z;
  int b = zz / SK, kc = zz % SK;
  int kchunk = K / SK;                    // must be a multiple of 16
  int kbeg = kc * kchunk, kend = kbeg + kchunk;
  const float* Ab = A + (size_t)b * M * K;
  const float* Bb = B + (size_t)b * K * N;
  __shared__ float As[16][68];
  __shared__ float Bs[16][64];
  int row0 = blockIdx.y * 64;
  int col0 = blockIdx.x * 64;
  int t = threadIdx.x;
  int tx = t & 15, ty = t >> 4;
  float acc[4][4] = {};
  int la_r = t >> 2;
  int la_k = (t & 3) << 2;
  int lb_r = t >> 4;
  int lb_c = (t & 15) << 2;
  const float* Aptr = Ab + (size_t)(row0 + la_r) * K + la_k;
  const float* Bptr = Bb + (size_t)lb_r * N + col0 + lb_c;
  float4 av = *(const float4*)(Aptr + kbeg);
  float4 bv = *(const float4*)(Bptr + (size_t)kbeg * N);
  for (int k0 = kbeg; k0 < kend; k0 += 16) {
    __syncthreads();
    As[la_k + 0][la_r] = av.x;
    As[la_k + 1][la_r] = av.y;
    As[la_k + 2][la_r] = av.z;
    As[la_k + 3][la_r] = av.w;
    *(float4*)&Bs[lb_r][lb_c] = bv;
    __syncthreads();
    if (k0 + 16 < kend) {
      av = *(const float4*)(Aptr + k0 + 16);
      bv = *(const float4*)(Bptr + (size_t)(k0 + 16) * N);
    }
#pragma unroll
    for (int k = 0; k < 16; ++k) {
      float4 a = *(const float4*)&As[k][ty << 2];
      float4 bq = *(const float4*)&Bs[k][tx << 2];
      float av4[4] = {a.x, a.y, a.z, a.w};
      float bv4[4] = {bq.x, bq.y, bq.z, bq.w};
#pragma unroll
      for (int ii = 0; ii < 4; ++ii)
#pragma unroll
        for (int jj = 0; jj < 4; ++jj)
          acc[ii][jj] = fmaf(av4[ii], bv4[jj], acc[ii][jj]);
    }
  }
  float* Cb = C + (size_t)b * M * N;
#pragma unroll
  for (int ii = 0; ii < 4; ++ii)
#pragma unroll
    for (int jj = 0; jj < 4; ++jj)
      atomicAdd(&Cb[(size_t)(row0 + (ty << 2) + ii) * N + col0 + (tx << 2) + jj],
                acc[ii][jj]);
}

// MFMA split-f16 GEMM — EXACT R1 kernel (measured 184us, MfmaUtil 27.9%).
// R2/R3's restructured epilogue collapsed it to ~650-700us with ~1GB of HBM
// writes (scratch-spill signature); restored verbatim, epilogue included.
__global__ __launch_bounds__(256, 2)
void mfma_fused_kernel(const _Float16* __restrict__ Ahi, const _Float16* __restrict__ Alo,
                       const _Float16* __restrict__ Bhi, const _Float16* __restrict__ Blo,
                       const float* __restrict__ up2, const float* __restrict__ up1,
                       unsigned long long* __restrict__ packed) {
  const int K = 576;
  // ---- XCD swizzle: grid is (32,32,2) = 2048 blocks; 2048 % 8 == 0 -> bijective
  int bid = (blockIdx.z * 32 + blockIdx.y) * 32 + blockIdx.x;
  int swz = (bid & 7) * 256 + (bid >> 3);
  int bx = swz & 31;
  int by = (swz >> 5) & 31;
  int b  = swz >> 10;

  int row0 = by * 128;   // ref axis (n) — argmax axis
  int col0 = bx * 128;   // lr axis (m) — output positions
  int t = threadIdx.x;
  int lane = t & 63, wave = t >> 6;
  int wy = wave & 1, wx = wave >> 1;
  int quad = lane >> 4, lm = lane & 15;

  // LDS: [buf:2][plane:4][8KB tile]. plane 0=AH 1=AL 2=BH 3=BL.
  __shared__ _Float16 lds[2 * 4 * 4096];

  // ---- staging source offsets (per-lane, bytes into a [128][K] half-plane).
  int off[2];
#pragma unroll
  for (int h = 0; h < 2; ++h) {
    int d = wave * 128 + h * 64 + lane;
    int line = d >> 3;
    int c3 = (d & 7) ^ (line & 7);
    int row = (line << 1) | (c3 >> 2);
    int c = c3 & 3;
    off[h] = row * (K * 2) + c * 16;
  }
  const char* pg[4];
  pg[0] = (const char*)Ahi + ((size_t)b * 4096 + row0) * (size_t)K * 2;
  pg[1] = (const char*)Alo + ((size_t)b * 4096 + row0) * (size_t)K * 2;
  pg[2] = (const char*)Bhi + ((size_t)b * 4096 + col0) * (size_t)K * 2;
  pg[3] = (const char*)Blo + ((size_t)b * 4096 + col0) * (size_t)K * 2;

  // ---- fragment ds_read addresses (bytes into an 8KB plane), swizzled.
  int ra[4], rb[4];
#pragma unroll
  for (int i = 0; i < 4; ++i) {
    int rowa = wy * 64 + i * 16 + lm;
    int la_ = rowa >> 1;
    ra[i] = la_ * 128 + (((((rowa & 1) << 2) | quad) ^ (la_ & 7)) << 4);
    int rowb = wx * 64 + i * 16 + lm;
    int lb_ = rowb >> 1;
    rb[i] = lb_ * 128 + (((((rowb & 1) << 2) | quad) ^ (lb_ & 7)) << 4);
  }

  f32x4 S1[4][4] = {};
  f32x4 S2[4][4] = {};

  // stage tile 0 into buf 0
#pragma unroll
  for (int p = 0; p < 4; ++p) {
    char* lb_ = (char*)lds + p * 8192 + wave * 2048;
    gload_lds16(pg[p] + off[0], lb_);
    gload_lds16(pg[p] + off[1], lb_ + 1024);
  }
  __syncthreads();

  int buf = 0;
  for (int t18 = 0; t18 < 18; ++t18) {
    const char* lb = (const char*)lds + buf * 32768;
    half8 aH[4], aL[4], bH[4], bL[4];
#pragma unroll
    for (int i = 0; i < 4; ++i) {
      aH[i] = *(const half8*)(lb + ra[i]);
      aL[i] = *(const half8*)(lb + 8192 + ra[i]);
      bH[i] = *(const half8*)(lb + 16384 + rb[i]);
      bL[i] = *(const half8*)(lb + 24576 + rb[i]);
    }
    // prefetch next tile into the other buffer; flies under the MFMA phase,
    // drained by the vmcnt(0) the compiler emits at the trailing barrier.
    if (t18 < 17) {
      int kbyte = (t18 + 1) * 64;
#pragma unroll
      for (int p = 0; p < 4; ++p) {
        char* lw = (char*)lds + (buf ^ 1) * 32768 + p * 8192 + wave * 2048;
        gload_lds16(pg[p] + kbyte + off[0], lw);
        gload_lds16(pg[p] + kbyte + off[1], lw + 1024);
      }
    }
#pragma unroll
    for (int i = 0; i < 4; ++i)
#pragma unroll
      for (int j = 0; j < 4; ++j) {
        S1[i][j] = __builtin_amdgcn_mfma_f32_16x16x32_f16(aH[i], bH[j], S1[i][j], 0, 0, 0);
        S2[i][j] = __builtin_amdgcn_mfma_f32_16x16x32_f16(aH[i], bL[j], S2[i][j], 0, 0, 0);
        S2[i][j] = __builtin_amdgcn_mfma_f32_16x16x32_f16(aL[i], bH[j], S2[i][j], 0, 0, 0);
      }
    __syncthreads();
    buf ^= 1;
  }

  // ---- fused epilogue: v = S1 + S2*2^-12; add bicubic taps; /3; max/argmax ----
  const float inv4096 = 1.0f / 4096.0f;
  const float* u2b = up2 + (size_t)b * 4096 * 1024;
  const float* u1b = up1 + (size_t)b * 4096 * 256;
#pragma unroll
  for (int j = 0; j < 4; ++j) {
    int gm = col0 + wx * 64 + j * 16 + lm;
    float src2 = (gm + 0.5f) * 0.25f - 0.5f;
    float f2 = floorf(src2); float t2 = src2 - f2; int i2 = (int)f2;
    int idx2[4]; float w2[4];
#pragma unroll
    for (int tp = 0; tp < 4; ++tp) {
      idx2[tp] = min(max(i2 + tp - 1, 0), 1023);
      w2[tp] = cubicw(t2 - (float)(tp - 1));
    }
    float src1 = (gm + 0.5f) * 0.0625f - 0.5f;
    float f1 = floorf(src1); float t1 = src1 - f1; int i1 = (int)f1;
    int idx1[4]; float w1[4];
#pragma unroll
    for (int tp = 0; tp < 4; ++tp) {
      idx1[tp] = min(max(i1 + tp - 1, 0), 255);
      w1[tp] = cubicw(t1 - (float)(tp - 1));
    }
    unsigned long long best = 0ull;
#pragma unroll
    for (int i = 0; i < 4; ++i) {
#pragma unroll
      for (int r = 0; r < 4; ++r) {
        int gn = row0 + wy * 64 + i * 16 + quad * 4 + r;
        float v = S1[i][j][r] + S2[i][j][r] * inv4096;
        const float* r2row = u2b + (size_t)gn * 1024;
        const float* r1row = u1b + (size_t)gn * 256;
        v += w2[0] * r2row[idx2[0]] + w2[1] * r2row[idx2[1]]
           + w2[2] * r2row[idx2[2]] + w2[3] * r2row[idx2[3]];
        v += w1[0] * r1row[idx1[0]] + w1[1] * r1row[idx1[1]]
           + w1[2] * r1row[idx1[2]] + w1[3] * r1row[idx1[3]];
        v *= (1.0f / 3.0f);
        unsigned int fb = __float_as_uint(v);
        unsigned int key = (fb & 0x80000000u) ? ~fb : (fb | 0x80000000u);
        unsigned long long pk = ((unsigned long long)key << 32)
                              | (unsigned long long)(0xFFFFFFFFu - (unsigned)gn);
        best = best > pk ? best : pk;
      }
    }
    // combine the 4 quads (same column gm, different row groups)
    unsigned long long o;
    o = __shfl_xor(best, 16); best = best > o ? best : o;
    o = __shfl_xor(best, 32); best = best > o ? best : o;
    if (lane < 16) atomicMax(&packed[(size_t)b * 4096 + gm], best);
  }
}

__global__ void finalize_kernel(const unsigned long long* __restrict__ packed,
                                float* __restrict__ s3_out, int* __restrict__ arg, int total) {
  int i = blockIdx.x * blockDim.x + threadIdx.x;
  if (i >= total) return;
  unsigned long long pk = packed[i];
  unsigned int key = (unsigned int)(pk >> 32);
  unsigned int fb = (key & 0x80000000u) ? (key ^ 0x80000000u) : ~key;
  s3_out[i] = __uint_as_float(fb);
  arg[i] = (int)(0xFFFFFFFFu - (unsigned int)(pk & 0xFFFFFFFFull));
}

// Batched 2D transpose: out[b][s][r] = in[b][r][s].  R, S multiples of 32.
__global__ __launch_bounds__(256)
void transpose_kernel(const float* __restrict__ in, float* __restrict__ out,
                      int R, int S) {
  __shared__ float tile[32][33];
  int b = blockIdx.z;
  int s0 = blockIdx.x * 32, r0 = blockIdx.y * 32;
  int tx = threadIdx.x & 31, ty = threadIdx.x >> 5;   // ty in 0..7
  const float* ib = in + (size_t)b * R * S;
  float* ob = out + (size_t)b * R * S;
#pragma unroll
  for (int k = 0; k < 4; ++k)
    tile[ty + 8 * k][tx] = ib[(size_t)(r0 + ty + 8 * k) * S + s0 + tx];
  __syncthreads();
#pragma unroll
  for (int k = 0; k < 4; ++k)
    ob[(size_t)(s0 + ty + 8 * k) * R + r0 + tx] = tile[tx][ty + 8 * k];
}

// Channel-last fold-gather: lanes map to c (fastest dim) so every tap is a
// contiguous C*4B read from refT [b][h][w][c]; writes TT [b][h][w][c].
template<int KK, int SS, int PP, int CL2, int WL2>
__global__ void fold_gather_cl_kernel(const float* __restrict__ refT,
                                      const int* __restrict__ arg,
                                      float* __restrict__ TT, int total) {
  const int C = 1 << CL2, W = 1 << WL2;
  int i = blockIdx.x * blockDim.x + threadIdx.x;
  if (i >= total) return;
  int c = i & (C - 1);
  int p = i >> CL2;                 // p = (b*H + h)*W + w   (H == W)
  int w = p & (W - 1);
  int h = (p >> WL2) & (W - 1);
  int b = p >> (2 * WL2);
  int y = h + PP, x = w + PP;
  int ho_lo = (y - KK + 1) > 0 ? (y - KK + 1 + SS - 1) / SS : 0;
  int ho_hi = min(63, y / SS);
  int wo_lo = (x - KK + 1) > 0 ? (x - KK + 1 + SS - 1) / SS : 0;
  int wo_hi = min(63, x / SS);
  const int* argb = arg + b * 4096;
  const float* refb = refT + ((size_t)b << (2 * WL2 + CL2));
  float acc = 0.f;
  for (int ho = ho_lo; ho <= ho_hi; ++ho) {
    int ki = y - SS * ho;
    for (int wo = wo_lo; wo <= wo_hi; ++wo) {
      int kj = x - SS * wo;
      int q = argb[(ho << 6) + wo];
      int qh = q >> 6, qw = q & 63;
      int ry = SS * qh + ki - PP;
      int rx = SS * qw + kj - PP;
      if (ry >= 0 && ry < W && rx >= 0 && rx < W)
        acc += refb[(((size_t)ry << WL2) + rx << CL2) + c];
    }
  }
  TT[(size_t)p * C + c] = acc * (1.0f / 9.0f);
}

extern "C" void kernel_launch(void* const* d_in, const int* in_sizes, int n_in,
                              void* d_out, int out_size, void* d_ws, size_t ws_size,
                              hipStream_t stream) {
  const float* lrsr1 = (const float*)d_in[0];
  const float* lrsr2 = (const float*)d_in[1];
  const float* lrsr3 = (const float*)d_in[2];
  const float* refsr1 = (const float*)d_in[3];
  const float* refsr2 = (const float*)d_in[4];
  const float* refsr3 = (const float*)d_in[5];
  const float* ref1 = (const float*)d_in[6];
  const float* ref2 = (const float*)d_in[7];
  const float* ref3 = (const float*)d_in[8];
  float* out = (float*)d_out;
  float* ws = (float*)d_ws;

  const int B = 2;
  // R1-proven workspace layout (n-upsampled up2/up1)
  size_t off_planes = 0;
  size_t off_r2n = off_planes + (size_t)B * 4096 * 576 * 2; // floats (= 4 half-planes)
  size_t off_l2n = off_r2n + (size_t)B * 1024 * 1152;   // [2,1152,1024]
  size_t off_r1n = off_l2n + (size_t)B * 1152 * 1024;   // [2,256,2304]
  size_t off_l1n = off_r1n + (size_t)B * 256 * 2304;    // [2,2304,256]
  size_t off_R2  = off_l1n + (size_t)B * 2304 * 256;    // [2,1024,1024]
  size_t off_R1  = off_R2  + (size_t)B * 1024 * 1024;   // [2,256,256]
  size_t off_up2 = off_R1  + (size_t)B * 256 * 256;     // [2,4096,1024] (n-upsampled)
  size_t off_up1 = off_up2 + (size_t)B * 4096 * 1024;   // [2,4096,256]
  size_t off_S   = off_up1 + (size_t)B * 4096 * 256;    // [2,4096]
  size_t off_invn= off_S   + (size_t)B * 4096;          // [2,4096]
  size_t off_pk  = off_invn+ (size_t)B * 4096;          // [2,4096] u64
  size_t off_arg = off_pk  + (size_t)B * 4096 * 2;      // [2,4096] int

  const size_t PLANE = (size_t)B * 4096 * 576;          // halves per plane
  _Float16* r3hi = (_Float16*)(ws + off_planes);
  _Float16* r3lo = r3hi + PLANE;
  _Float16* l3hi = r3lo + PLANE;
  _Float16* l3lo = l3hi + PLANE;

  auto run_desc32 = [&](const float* x, int C, int H, int W, float* outbuf, bool r_layout) {
    int HW = H * W;
    int tS = B * HW;
    sumsq_kernel<<<DIVUP(tS, 256), 256, 0, stream>>>(x, ws + off_S, C, HW, tS);
    invnorm_kernel<<<DIVUP(tS, 256), 256, 0, stream>>>(ws + off_S, ws + off_invn, H, W, tS);
    int tD = B * C * 9 * HW;
    if (r_layout)
      desc_r_kernel<<<DIVUP(tD, 256), 256, 0, stream>>>(x, ws + off_invn, outbuf, C, H, W, tD);
    else
      desc_l_kernel<<<DIVUP(tD, 256), 256, 0, stream>>>(x, ws + off_invn, outbuf, C, H, W, tD);
  };
  auto run_desc_split = [&](const float* x, _Float16* hi, _Float16* lo) {
    int C = 64, H = 64, W = 64, HW = H * W;
    int tS = B * HW;
    sumsq_kernel<<<DIVUP(tS, 256), 256, 0, stream>>>(x, ws + off_S, C, HW, tS);
    invnorm_kernel<<<DIVUP(tS, 256), 256, 0, stream>>>(ws + off_S, ws + off_invn, H, W, tS);
    int tD = B * C * HW;
    desc_split_kernel<<<DIVUP(tD, 256), 256, 0, stream>>>(x, ws + off_invn, hi, lo, C, H, W, tD);
  };

  // level 3 split-f16 descriptors (both pixel-major [4096][576])
  run_desc_split(refsr3, r3hi, r3lo);
  run_desc_split(lrsr3, l3hi, l3lo);
  // levels 1/2 fp32 descriptors
  run_desc32(lrsr2, 128, 32, 32, ws + off_l2n, false);
  run_desc32(refsr2, 128, 32, 32, ws + off_r2n, true);
  run_desc32(lrsr1, 256, 16, 16, ws + off_l1n, false);
  run_desc32(refsr1, 256, 16, 16, ws + off_r1n, true);

  // small correlation GEMMs R2 (plain), R1 (split-K x8, 256 blocks)
  {
    dim3 g(1024 / 64, 1024 / 64, B);
    gemm64_kernel<<<g, 256, 0, stream>>>(ws + off_r2n, ws + off_l2n, ws + off_R2,
                                         1024, 1024, 1152);
  }
  {
    init_packed_kernel<<<DIVUP(65536, 256), 256, 0, stream>>>(
        (unsigned long long*)(ws + off_R1), 65536);   // zero R1 (2*256*256 f32)
    dim3 g(256 / 64, 256 / 64, B * 8);
    gemm64sk_kernel<<<g, 256, 0, stream>>>(ws + off_r1n, ws + off_l1n, ws + off_R1,
                                           256, 256, 2304, 8);
  }

  // axis-1 bicubic upsample of R2 (x4) and R1 (x16) to 4096 rows (R1 layout)
  {
    int tU2 = B * 4096 * 1024;
    upsample_n_kernel<<<DIVUP(tU2, 256), 256, 0, stream>>>(ws + off_R2, ws + off_up2,
                                                           1024, 1024, 0.25f, tU2);
    int tU1 = B * 4096 * 256;
    upsample_n_kernel<<<DIVUP(tU1, 256), 256, 0, stream>>>(ws + off_R1, ws + off_up1,
                                                           256, 256, 0.0625f, tU1);
  }

  unsigned long long* pk = (unsigned long long*)(ws + off_pk);
  init_packed_kernel<<<DIVUP(B * 4096, 256), 256, 0, stream>>>(pk, B * 4096);

  // fused R3 MFMA GEMM + bicubic add + max/argmax
  {
    dim3 g(4096 / 128, 4096 / 128, B);
    mfma_fused_kernel<<<g, 256, 0, stream>>>(r3hi, r3lo, l3hi, l3lo,
                                             ws + off_up2, ws + off_up1, pk);
  }

  int* argp = (int*)(ws + off_arg);
  finalize_kernel<<<DIVUP(B * 4096, 256), 256, 0, stream>>>(pk, out, argp, B * 4096);

  // transfer: fold(gather(unfold(ref_lvX)))/9 — channel-last pipeline.
  // Dead regions reused: refT at ws+0 (planes region, 9.44M floats),
  // TT at ws+off_up2 (8.39M floats; up2 is dead after mfma_fused).
  float* refT = ws + off_planes;
  float* TT = ws + off_up2;
  float* T3 = out + 8192;
  float* T2 = T3 + (size_t)B * 256 * 64 * 64;
  float* T1 = T2 + (size_t)B * 128 * 128 * 128;
  // ---- T3: C=256, P=4096 (64x64)
  {
    dim3 g1(4096 / 32, 256 / 32, B);
    transpose_kernel<<<g1, 256, 0, stream>>>(ref3, refT, 256, 4096);
    int tt = B * 4096 * 256;
    fold_gather_cl_kernel<3, 1, 1, 8, 6><<<DIVUP(tt, 256), 256, 0, stream>>>(refT, argp, TT, tt);
    dim3 g2(256 / 32, 4096 / 32, B);
    transpose_kernel<<<g2, 256, 0, stream>>>(TT, T3, 4096, 256);
  }
  // ---- T2: C=128, P=16384 (128x128)
  {
    dim3 g1(16384 / 32, 128 / 32, B);
    transpose_kernel<<<g1, 256, 0, stream>>>(ref2, refT, 128, 16384);
    int tt = B * 16384 * 128;
    fold_gather_cl_kernel<6, 2, 2, 7, 7><<<DIVUP(tt, 256), 256, 0, stream>>>(refT, argp, TT, tt);
    dim3 g2(128 / 32, 16384 / 32, B);
    transpose_kernel<<<g2, 256, 0, stream>>>(TT, T2, 16384, 128);
  }
  // ---- T1: C=64, P=65536 (256x256)
  {
    dim3 g1(65536 / 32, 64 / 32, B);
    transpose_kernel<<<g1, 256, 0, stream>>>(ref1, refT, 64, 65536);
    int tt = B * 65536 * 64;
    fold_gather_cl_kernel<12, 4, 4, 6, 8><<<DIVUP(tt, 256), 256, 0, stream>>>(refT, argp, TT, tt);
    dim3 g2(64 / 32, 65536 / 32, B);
    transpose_kernel<<<g2, 256, 0, stream>>>(TT, T1, 65536, 64);
  }
}

// Round 5
// 664.023 us; speedup vs baseline: 2.3128x; 1.6774x over previous
//
#include <hip/hip_runtime.h>
#include <cstdint>

#define DIVUP(a,b) (((a)+(b)-1)/(b))

typedef __attribute__((ext_vector_type(4))) float f32x4;
typedef __attribute__((ext_vector_type(8))) _Float16 half8;

// Direct global->LDS DMA, 16B per lane. LDS dest is WAVE-UNIFORM base + lane*16.
__device__ __forceinline__ void gload_lds16(const void* g, void* l) {
  __builtin_amdgcn_global_load_lds(
      (const __attribute__((address_space(1))) void*)g,
      (__attribute__((address_space(3))) void*)l, 16, 0, 0);
}

__device__ __forceinline__ float cubicw(float x) {
  // PyTorch bicubic kernel, a = -0.75
  float ax = fabsf(x);
  float ax2 = ax * ax;
  float ax3 = ax2 * ax;
  if (ax <= 1.0f) return 1.25f * ax3 - 2.25f * ax2 + 1.0f;
  if (ax < 2.0f)  return -0.75f * ax3 + 3.75f * ax2 - 6.0f * ax + 3.0f;
  return 0.0f;
}

// ---------------- multi-job S = per-pixel channel sumsq ----------------
// jobs (block ranges): [0,32) refsr3 C64 HW4096 so=0 | [32,64) lrsr3 so=8192 |
// [64,72) refsr2 C128 HW1024 so=16384 | [72,80) lrsr2 so=18432 |
// [80,82) refsr1 C256 HW256 so=20480 | [82,84) lrsr1 so=20992
__global__ void sumsq_multi(const float* __restrict__ r3, const float* __restrict__ l3,
                            const float* __restrict__ r2, const float* __restrict__ l2,
                            const float* __restrict__ r1, const float* __restrict__ l1,
                            float* __restrict__ S) {
  int blk = blockIdx.x;
  const float* x; int C, HW, so, base;
  if (blk < 32)      { x = r3; C = 64;  HW = 4096; so = 0;     base = 0;  }
  else if (blk < 64) { x = l3; C = 64;  HW = 4096; so = 8192;  base = 32; }
  else if (blk < 72) { x = r2; C = 128; HW = 1024; so = 16384; base = 64; }
  else if (blk < 80) { x = l2; C = 128; HW = 1024; so = 18432; base = 72; }
  else if (blk < 82) { x = r1; C = 256; HW = 256;  so = 20480; base = 80; }
  else               { x = l1; C = 256; HW = 256;  so = 20992; base = 82; }
  int i = (blk - base) * 256 + threadIdx.x;
  if (i >= 2 * HW) return;
  int pix = i % HW, b = i / HW;
  const float* p = x + (size_t)b * C * HW + pix;
  float s = 0.f;
  for (int c = 0; c < C; ++c) { float v = p[(size_t)c * HW]; s += v * v; }
  S[so + i] = s;
}

// ---------------- multi-job invn = 1/max(sqrt(3x3 sum of S),1e-12) ------
__global__ void invnorm_multi(const float* __restrict__ S, float* __restrict__ invn) {
  int blk = blockIdx.x;
  int H, so, base;
  if (blk < 32)      { H = 64; so = 0;     base = 0;  }
  else if (blk < 64) { H = 64; so = 8192;  base = 32; }
  else if (blk < 72) { H = 32; so = 16384; base = 64; }
  else if (blk < 80) { H = 32; so = 18432; base = 72; }
  else if (blk < 82) { H = 16; so = 20480; base = 80; }
  else               { H = 16; so = 20992; base = 82; }
  int W = H;
  int i = (blk - base) * 256 + threadIdx.x;
  if (i >= 2 * H * W) return;
  int p = i % (H * W), b = i / (H * W);
  int ph = p / W, pw = p % W;
  const float* Sb = S + so + (size_t)b * H * W;
  float s = 0.f;
  for (int ki = 0; ki < 3; ++ki) {
    int y = ph + ki - 1;
    if (y < 0 || y >= H) continue;
    for (int kj = 0; kj < 3; ++kj) {
      int xx = pw + kj - 1;
      if (xx < 0 || xx >= W) continue;
      s += Sb[y * W + xx];
    }
  }
  float n = fmaxf(sqrtf(s), 1e-12f);
  invn[so + i] = 1.0f / n;
}

// ---------------- multi-job level-3 split-f16 descriptors ----------------
// job0 (blocks [0,2048)): refsr3 -> r3hi/r3lo, io=0
// job1 (blocks [2048,4096)): lrsr3 -> l3hi/l3lo, io=8192
__global__ void desc_split_multi(const float* __restrict__ r3, const float* __restrict__ l3,
                                 _Float16* __restrict__ r3hi, _Float16* __restrict__ r3lo,
                                 _Float16* __restrict__ l3hi, _Float16* __restrict__ l3lo,
                                 const float* __restrict__ invn) {
  const int C = 64, H = 64, W = 64;
  int blk = blockIdx.x;
  int job = blk >> 11;
  const float* x = job ? l3 : r3;
  _Float16* hi = job ? l3hi : r3hi;
  _Float16* lo = job ? l3lo : r3lo;
  int io = job ? 8192 : 0;
  int i = (blk & 2047) * 256 + threadIdx.x;
  if (i >= 2 * C * H * W) return;
  int c = i % C;
  int p = (i / C) % (H * W);
  int b = i / (C * H * W);
  int ph = p / W, pw = p % W;
  float s = invn[io + b * H * W + p];
  size_t obase = ((size_t)b * H * W + p) * (size_t)(C * 9) + (size_t)c * 9;
  const float* xb = x + (size_t)(b * C + c) * H * W;
#pragma unroll
  for (int r = 0; r < 9; ++r) {
    int y = ph + r / 3 - 1, xx = pw + r % 3 - 1;
    float v = 0.f;
    if (y >= 0 && y < H && xx >= 0 && xx < W) v = xb[y * W + xx] * s;
    _Float16 h = (_Float16)v;
    float hf = (float)h;
    _Float16 l = (_Float16)((v - hf) * 4096.0f);
    hi[obase + r] = h;
    lo[obase + r] = l;
  }
}

// ---------------- multi-job l-layout descriptors (levels 2,1) ------------
// job0 (blocks [0,9216)): lrsr2 C=128 H=32 io=18432 -> l2n
// job1 (blocks [9216,13824)): lrsr1 C=256 H=16 io=20992 -> l1n
__global__ void desc_l_multi(const float* __restrict__ l2in, const float* __restrict__ l1in,
                             float* __restrict__ l2n, float* __restrict__ l1n,
                             const float* __restrict__ invn) {
  int blk = blockIdx.x;
  const float* x; float* out; int C, H, io, base;
  if (blk < 9216) { x = l2in; out = l2n; C = 128; H = 32; io = 18432; base = 0; }
  else            { x = l1in; out = l1n; C = 256; H = 16; io = 20992; base = 9216; }
  int W = H, HW = H * W, D = C * 9;
  int i = (blk - base) * 256 + threadIdx.x;
  if (i >= 2 * D * HW) return;
  int p = i % HW;
  int d = (i / HW) % D;
  int b = i / (HW * D);
  int c = d / 9, r = d % 9, ki = r / 3, kj = r % 3;
  int ph = p / W, pw = p % W;
  int y = ph + ki - 1, xx = pw + kj - 1;
  float v = 0.f;
  if (y >= 0 && y < H && xx >= 0 && xx < W) v = x[((size_t)(b * C + c) * H + y) * W + xx];
  out[i] = v * invn[io + b * HW + p];
}

// ---------------- multi-job r-layout descriptors (levels 2,1) ------------
__global__ void desc_r_multi(const float* __restrict__ r2in, const float* __restrict__ r1in,
                             float* __restrict__ r2n, float* __restrict__ r1n,
                             const float* __restrict__ invn) {
  int blk = blockIdx.x;
  const float* x; float* out; int C, H, io, base;
  if (blk < 9216) { x = r2in; out = r2n; C = 128; H = 32; io = 16384; base = 0; }
  else            { x = r1in; out = r1n; C = 256; H = 16; io = 20480; base = 9216; }
  int W = H, HW = H * W, D = C * 9;
  int i = (blk - base) * 256 + threadIdx.x;
  if (i >= 2 * D * HW) return;
  int d = i % D;
  int p = (i / D) % HW;
  int b = i / (D * HW);
  int c = d / 9, r = d % 9, ki = r / 3, kj = r % 3;
  int ph = p / W, pw = p % W;
  int y = ph + ki - 1, xx = pw + kj - 1;
  float v = 0.f;
  if (y >= 0 && y < H && xx >= 0 && xx < W) v = x[((size_t)(b * C + c) * H + y) * W + xx];
  out[i] = v * invn[io + b * HW + p];
}

// ---------------- multi-job axis-1 bicubic upsample to 4096 rows --------
// job0 (blocks [0,32768)): R2 Nin=1024 cols=1024 x4 -> up2
// job1 (blocks [32768,40960)): R1 Nin=256 cols=256 x16 -> up1
__global__ void upsample_multi(const float* __restrict__ R2, const float* __restrict__ R1,
                               float* __restrict__ up2, float* __restrict__ up1) {
  int blk = blockIdx.x;
  const float* Rin; float* out; int Nin, cols, base; float invscale;
  if (blk < 32768) { Rin = R2; out = up2; Nin = 1024; cols = 1024; invscale = 0.25f;   base = 0; }
  else             { Rin = R1; out = up1; Nin = 256;  cols = 256;  invscale = 0.0625f; base = 32768; }
  int i = (blk - base) * 256 + threadIdx.x;
  if (i >= 2 * 4096 * cols) return;
  int j = i % cols;
  int n = (i / cols) & 4095;
  int b = i / (cols * 4096);
  float src = (n + 0.5f) * invscale - 0.5f;
  float f = floorf(src);
  float tt = src - f;
  int fi = (int)f;
  const float* Rb = Rin + (size_t)b * Nin * cols;
  float s = 0.f;
#pragma unroll
  for (int tp = 0; tp < 4; ++tp) {
    int ii = min(max(fi + tp - 1, 0), Nin - 1);
    s += cubicw(tt - (float)(tp - 1)) * Rb[(size_t)ii * cols + j];
  }
  out[i] = s;
}

// zero R1 (65536 u64) + packed (8192 u64) in one dispatch
__global__ void init_multi(unsigned long long* __restrict__ R1z,
                           unsigned long long* __restrict__ pk) {
  int i = blockIdx.x * blockDim.x + threadIdx.x;
  if (i < 65536) R1z[i] = 0ull;
  else if (i < 65536 + 8192) pk[i - 65536] = 0ull;
}

// 64x64-tile fp32 GEMM (4x4 microtile), register-prefetch pipelined. R2.
__global__ __launch_bounds__(256)
void gemm64_kernel(const float* __restrict__ A, const float* __restrict__ B,
                   float* __restrict__ C, int M, int N, int K) {
  int b = blockIdx.z;
  const float* Ab = A + (size_t)b * M * K;
  const float* Bb = B + (size_t)b * K * N;
  __shared__ float As[16][68];
  __shared__ float Bs[16][64];
  int row0 = blockIdx.y * 64;
  int col0 = blockIdx.x * 64;
  int t = threadIdx.x;
  int tx = t & 15, ty = t >> 4;
  float acc[4][4] = {};
  int la_r = t >> 2;
  int la_k = (t & 3) << 2;
  int lb_r = t >> 4;
  int lb_c = (t & 15) << 2;
  const float* Aptr = Ab + (size_t)(row0 + la_r) * K + la_k;
  const float* Bptr = Bb + (size_t)lb_r * N + col0 + lb_c;
  float4 av = *(const float4*)(Aptr);
  float4 bv = *(const float4*)(Bptr);
  for (int k0 = 0; k0 < K; k0 += 16) {
    __syncthreads();
    As[la_k + 0][la_r] = av.x;
    As[la_k + 1][la_r] = av.y;
    As[la_k + 2][la_r] = av.z;
    As[la_k + 3][la_r] = av.w;
    *(float4*)&Bs[lb_r][lb_c] = bv;
    __syncthreads();
    if (k0 + 16 < K) {
      av = *(const float4*)(Aptr + k0 + 16);
      bv = *(const float4*)(Bptr + (size_t)(k0 + 16) * N);
    }
#pragma unroll
    for (int k = 0; k < 16; ++k) {
      float4 a = *(const float4*)&As[k][ty << 2];
      float4 bq = *(const float4*)&Bs[k][tx << 2];
      float av4[4] = {a.x, a.y, a.z, a.w};
      float bv4[4] = {bq.x, bq.y, bq.z, bq.w};
#pragma unroll
      for (int ii = 0; ii < 4; ++ii)
#pragma unroll
        for (int jj = 0; jj < 4; ++jj)
          acc[ii][jj] = fmaf(av4[ii], bv4[jj], acc[ii][jj]);
    }
  }
  float* Cb = C + (size_t)b * M * N;
#pragma unroll
  for (int ii = 0; ii < 4; ++ii) {
    float4 v = make_float4(acc[ii][0], acc[ii][1], acc[ii][2], acc[ii][3]);
    *(float4*)&Cb[(size_t)(row0 + (ty << 2) + ii) * N + col0 + (tx << 2)] = v;
  }
}

// Split-K variant with atomicAdd epilogue (tiny R1 GEMM; SK=8 -> 256 blocks).
__global__ __launch_bounds__(256)
void gemm64sk_kernel(const float* __restrict__ A, const float* __restrict__ B,
                     float* __restrict__ C, int M, int N, int K, int SK) {
  int zz = blockIdx.z;
  int b = zz / SK, kc = zz % SK;
  int kchunk = K / SK;
  int kbeg = kc * kchunk, kend = kbeg + kchunk;
  const float* Ab = A + (size_t)b * M * K;
  const float* Bb = B + (size_t)b * K * N;
  __shared__ float As[16][68];
  __shared__ float Bs[16][64];
  int row0 = blockIdx.y * 64;
  int col0 = blockIdx.x * 64;
  int t = threadIdx.x;
  int tx = t & 15, ty = t >> 4;
  float acc[4][4] = {};
  int la_r = t >> 2;
  int la_k = (t & 3) << 2;
  int lb_r = t >> 4;
  int lb_c = (t & 15) << 2;
  const float* Aptr = Ab + (size_t)(row0 + la_r) * K + la_k;
  const float* Bptr = Bb + (size_t)lb_r * N + col0 + lb_c;
  float4 av = *(const float4*)(Aptr + kbeg);
  float4 bv = *(const float4*)(Bptr + (size_t)kbeg * N);
  for (int k0 = kbeg; k0 < kend; k0 += 16) {
    __syncthreads();
    As[la_k + 0][la_r] = av.x;
    As[la_k + 1][la_r] = av.y;
    As[la_k + 2][la_r] = av.z;
    As[la_k + 3][la_r] = av.w;
    *(float4*)&Bs[lb_r][lb_c] = bv;
    __syncthreads();
    if (k0 + 16 < kend) {
      av = *(const float4*)(Aptr + k0 + 16);
      bv = *(const float4*)(Bptr + (size_t)(k0 + 16) * N);
    }
#pragma unroll
    for (int k = 0; k < 16; ++k) {
      float4 a = *(const float4*)&As[k][ty << 2];
      float4 bq = *(const float4*)&Bs[k][tx << 2];
      float av4[4] = {a.x, a.y, a.z, a.w};
      float bv4[4] = {bq.x, bq.y, bq.z, bq.w};
#pragma unroll
      for (int ii = 0; ii < 4; ++ii)
#pragma unroll
        for (int jj = 0; jj < 4; ++jj)
          acc[ii][jj] = fmaf(av4[ii], bv4[jj], acc[ii][jj]);
    }
  }
  float* Cb = C + (size_t)b * M * N;
#pragma unroll
  for (int ii = 0; ii < 4; ++ii)
#pragma unroll
    for (int jj = 0; jj < 4; ++jj)
      atomicAdd(&Cb[(size_t)(row0 + (ty << 2) + ii) * N + col0 + (tx << 2) + jj],
                acc[ii][jj]);
}

// MFMA split-f16 GEMM — EXACT R1 kernel (184us, MfmaUtil 27.5%). DO NOT TOUCH:
// epilogue restructures spill the K-loop accumulators (R2/R3: 650-700us, 1GB
// of scratch writes). Verified restored in R4.
__global__ __launch_bounds__(256, 2)
void mfma_fused_kernel(const _Float16* __restrict__ Ahi, const _Float16* __restrict__ Alo,
                       const _Float16* __restrict__ Bhi, const _Float16* __restrict__ Blo,
                       const float* __restrict__ up2, const float* __restrict__ up1,
                       unsigned long long* __restrict__ packed) {
  const int K = 576;
  int bid = (blockIdx.z * 32 + blockIdx.y) * 32 + blockIdx.x;
  int swz = (bid & 7) * 256 + (bid >> 3);
  int bx = swz & 31;
  int by = (swz >> 5) & 31;
  int b  = swz >> 10;

  int row0 = by * 128;
  int col0 = bx * 128;
  int t = threadIdx.x;
  int lane = t & 63, wave = t >> 6;
  int wy = wave & 1, wx = wave >> 1;
  int quad = lane >> 4, lm = lane & 15;

  __shared__ _Float16 lds[2 * 4 * 4096];

  int off[2];
#pragma unroll
  for (int h = 0; h < 2; ++h) {
    int d = wave * 128 + h * 64 + lane;
    int line = d >> 3;
    int c3 = (d & 7) ^ (line & 7);
    int row = (line << 1) | (c3 >> 2);
    int c = c3 & 3;
    off[h] = row * (K * 2) + c * 16;
  }
  const char* pg[4];
  pg[0] = (const char*)Ahi + ((size_t)b * 4096 + row0) * (size_t)K * 2;
  pg[1] = (const char*)Alo + ((size_t)b * 4096 + row0) * (size_t)K * 2;
  pg[2] = (const char*)Bhi + ((size_t)b * 4096 + col0) * (size_t)K * 2;
  pg[3] = (const char*)Blo + ((size_t)b * 4096 + col0) * (size_t)K * 2;

  int ra[4], rb[4];
#pragma unroll
  for (int i = 0; i < 4; ++i) {
    int rowa = wy * 64 + i * 16 + lm;
    int la_ = rowa >> 1;
    ra[i] = la_ * 128 + (((((rowa & 1) << 2) | quad) ^ (la_ & 7)) << 4);
    int rowb = wx * 64 + i * 16 + lm;
    int lb_ = rowb >> 1;
    rb[i] = lb_ * 128 + (((((rowb & 1) << 2) | quad) ^ (lb_ & 7)) << 4);
  }

  f32x4 S1[4][4] = {};
  f32x4 S2[4][4] = {};

#pragma unroll
  for (int p = 0; p < 4; ++p) {
    char* lb_ = (char*)lds + p * 8192 + wave * 2048;
    gload_lds16(pg[p] + off[0], lb_);
    gload_lds16(pg[p] + off[1], lb_ + 1024);
  }
  __syncthreads();

  int buf = 0;
  for (int t18 = 0; t18 < 18; ++t18) {
    const char* lb = (const char*)lds + buf * 32768;
    half8 aH[4], aL[4], bH[4], bL[4];
#pragma unroll
    for (int i = 0; i < 4; ++i) {
      aH[i] = *(const half8*)(lb + ra[i]);
      aL[i] = *(const half8*)(lb + 8192 + ra[i]);
      bH[i] = *(const half8*)(lb + 16384 + rb[i]);
      bL[i] = *(const half8*)(lb + 24576 + rb[i]);
    }
    if (t18 < 17) {
      int kbyte = (t18 + 1) * 64;
#pragma unroll
      for (int p = 0; p < 4; ++p) {
        char* lw = (char*)lds + (buf ^ 1) * 32768 + p * 8192 + wave * 2048;
        gload_lds16(pg[p] + kbyte + off[0], lw);
        gload_lds16(pg[p] + kbyte + off[1], lw + 1024);
      }
    }
#pragma unroll
    for (int i = 0; i < 4; ++i)
#pragma unroll
      for (int j = 0; j < 4; ++j) {
        S1[i][j] = __builtin_amdgcn_mfma_f32_16x16x32_f16(aH[i], bH[j], S1[i][j], 0, 0, 0);
        S2[i][j] = __builtin_amdgcn_mfma_f32_16x16x32_f16(aH[i], bL[j], S2[i][j], 0, 0, 0);
        S2[i][j] = __builtin_amdgcn_mfma_f32_16x16x32_f16(aL[i], bH[j], S2[i][j], 0, 0, 0);
      }
    __syncthreads();
    buf ^= 1;
  }

  const float inv4096 = 1.0f / 4096.0f;
  const float* u2b = up2 + (size_t)b * 4096 * 1024;
  const float* u1b = up1 + (size_t)b * 4096 * 256;
#pragma unroll
  for (int j = 0; j < 4; ++j) {
    int gm = col0 + wx * 64 + j * 16 + lm;
    float src2 = (gm + 0.5f) * 0.25f - 0.5f;
    float f2 = floorf(src2); float t2 = src2 - f2; int i2 = (int)f2;
    int idx2[4]; float w2[4];
#pragma unroll
    for (int tp = 0; tp < 4; ++tp) {
      idx2[tp] = min(max(i2 + tp - 1, 0), 1023);
      w2[tp] = cubicw(t2 - (float)(tp - 1));
    }
    float src1 = (gm + 0.5f) * 0.0625f - 0.5f;
    float f1 = floorf(src1); float t1 = src1 - f1; int i1 = (int)f1;
    int idx1[4]; float w1[4];
#pragma unroll
    for (int tp = 0; tp < 4; ++tp) {
      idx1[tp] = min(max(i1 + tp - 1, 0), 255);
      w1[tp] = cubicw(t1 - (float)(tp - 1));
    }
    unsigned long long best = 0ull;
#pragma unroll
    for (int i = 0; i < 4; ++i) {
#pragma unroll
      for (int r = 0; r < 4; ++r) {
        int gn = row0 + wy * 64 + i * 16 + quad * 4 + r;
        float v = S1[i][j][r] + S2[i][j][r] * inv4096;
        const float* r2row = u2b + (size_t)gn * 1024;
        const float* r1row = u1b + (size_t)gn * 256;
        v += w2[0] * r2row[idx2[0]] + w2[1] * r2row[idx2[1]]
           + w2[2] * r2row[idx2[2]] + w2[3] * r2row[idx2[3]];
        v += w1[0] * r1row[idx1[0]] + w1[1] * r1row[idx1[1]]
           + w1[2] * r1row[idx1[2]] + w1[3] * r1row[idx1[3]];
        v *= (1.0f / 3.0f);
        unsigned int fb = __float_as_uint(v);
        unsigned int key = (fb & 0x80000000u) ? ~fb : (fb | 0x80000000u);
        unsigned long long pk = ((unsigned long long)key << 32)
                              | (unsigned long long)(0xFFFFFFFFu - (unsigned)gn);
        best = best > pk ? best : pk;
      }
    }
    unsigned long long o;
    o = __shfl_xor(best, 16); best = best > o ? best : o;
    o = __shfl_xor(best, 32); best = best > o ? best : o;
    if (lane < 16) atomicMax(&packed[(size_t)b * 4096 + gm], best);
  }
}

__global__ void finalize_kernel(const unsigned long long* __restrict__ packed,
                                float* __restrict__ s3_out, int* __restrict__ arg, int total) {
  int i = blockIdx.x * blockDim.x + threadIdx.x;
  if (i >= total) return;
  unsigned long long pk = packed[i];
  unsigned int key = (unsigned int)(pk >> 32);
  unsigned int fb = (key & 0x80000000u) ? (key ^ 0x80000000u) : ~key;
  s3_out[i] = __uint_as_float(fb);
  arg[i] = (int)(0xFFFFFFFFu - (unsigned int)(pk & 0xFFFFFFFFull));
}

// ------------- batched multi-job 2D transpose (3 ref levels) -------------
// job0: ref3 [2][256][4096] -> refT3 ;  2048 blocks (gx=128, gy=8)
// job1: ref2 [2][128][16384] -> refT2 ; 4096 blocks (gx=512, gy=4)
// job2: ref1 [2][64][65536] -> refT1 ;  8192 blocks (gx=2048, gy=2)
__global__ __launch_bounds__(256)
void transpose_multi(const float* __restrict__ ref3, const float* __restrict__ ref2,
                     const float* __restrict__ ref1, float* __restrict__ o3,
                     float* __restrict__ o2, float* __restrict__ o1) {
  __shared__ float tile[32][33];
  int blk = blockIdx.x;
  const float* in; float* out; int R, S, gx, gy, base;
  if (blk < 2048)      { in = ref3; out = o3; R = 256; S = 4096;  gx = 128;  gy = 8; base = 0; }
  else if (blk < 6144) { in = ref2; out = o2; R = 128; S = 16384; gx = 512;  gy = 4; base = 2048; }
  else                 { in = ref1; out = o1; R = 64;  S = 65536; gx = 2048; gy = 2; base = 6144; }
  int local = blk - base;
  int pb = gx * gy;
  int b = local / pb;
  int rem = local % pb;
  int r0 = (rem / gx) * 32;
  int s0 = (rem % gx) * 32;
  int tx = threadIdx.x & 31, ty = threadIdx.x >> 5;
  const float* ib = in + (size_t)b * R * S;
  float* ob = out + (size_t)b * R * S;
#pragma unroll
  for (int k = 0; k < 4; ++k)
    tile[ty + 8 * k][tx] = ib[(size_t)(r0 + ty + 8 * k) * S + s0 + tx];
  __syncthreads();
#pragma unroll
  for (int k = 0; k < 4; ++k)
    ob[(size_t)(s0 + ty + 8 * k) * R + r0 + tx] = tile[tx][ty + 8 * k];
}

// ---- fold-gather, channel-last float4 reads + fused channel-first store ----
// Block = 16 consecutive w pixels (same h) x all C channels.
// thread: pl = tid>>4 (pixel), c4g = tid&15 (float4-channel group).
// Wave = 4 pixels x 16 c4 -> each tap read is 256B contiguous per pixel.
// LDS [C][16(+pad)] transpose -> coalesced channel-first global stores.
// FP accumulation order per (pixel,channel) identical to the reference loop.
template<int KK, int SS, int PP, int CL2, int WL2>
__global__ __launch_bounds__(256)
void foldT_kernel(const float* __restrict__ refT, const int* __restrict__ arg,
                  float* __restrict__ outCF) {
  const int C = 1 << CL2, W = 1 << WL2;
  const int NK = (C / 4) / 16;
  __shared__ float lds[C * 17];
  int tid = threadIdx.x;
  int pl = tid >> 4, c4g = tid & 15;
  int w0 = blockIdx.x * 16;
  int h = blockIdx.y;
  int b = blockIdx.z;
  int w = w0 + pl;
  int y = h + PP, x = w + PP;
  int ho_lo = (y - KK + 1) > 0 ? (y - KK + 1 + SS - 1) / SS : 0;
  int ho_hi = min(63, y / SS);
  int wo_lo = (x - KK + 1) > 0 ? (x - KK + 1 + SS - 1) / SS : 0;
  int wo_hi = min(63, x / SS);
  const int* argb = arg + b * 4096;
  const f32x4* refb4 = (const f32x4*)(refT + ((size_t)b << (2 * WL2 + CL2)));
  f32x4 acc[NK] = {};
  for (int ho = ho_lo; ho <= ho_hi; ++ho) {
    int ki = y - SS * ho;
    for (int wo = wo_lo; wo <= wo_hi; ++wo) {
      int kj = x - SS * wo;
      int q = argb[(ho << 6) + wo];
      int qh = q >> 6, qw = q & 63;
      int ry = SS * qh + ki - PP;
      int rx = SS * qw + kj - PP;
      if (ry >= 0 && ry < W && rx >= 0 && rx < W) {
        const f32x4* pb4 = refb4 + (((size_t)(ry << WL2) + rx) << (CL2 - 2));
#pragma unroll
        for (int k = 0; k < NK; ++k) acc[k] += pb4[c4g + k * 16];
      }
    }
  }
#pragma unroll
  for (int k = 0; k < NK; ++k) {
    int c4 = c4g + k * 16;
#pragma unroll
    for (int j = 0; j < 4; ++j)
      lds[(4 * c4 + j) * 17 + pl] = acc[k][j] * (1.0f / 9.0f);
  }
  __syncthreads();
  size_t ob = ((size_t)(b * C)) << (2 * WL2);
  for (int idx = tid; idx < C * 16; idx += 256) {
    int c = idx >> 4, j = idx & 15;
    outCF[ob + ((size_t)c << (2 * WL2)) + (h << WL2) + w0 + j] = lds[c * 17 + j];
  }
}

extern "C" void kernel_launch(void* const* d_in, const int* in_sizes, int n_in,
                              void* d_out, int out_size, void* d_ws, size_t ws_size,
                              hipStream_t stream) {
  const float* lrsr1 = (const float*)d_in[0];
  const float* lrsr2 = (const float*)d_in[1];
  const float* lrsr3 = (const float*)d_in[2];
  const float* refsr1 = (const float*)d_in[3];
  const float* refsr2 = (const float*)d_in[4];
  const float* refsr3 = (const float*)d_in[5];
  const float* ref1 = (const float*)d_in[6];
  const float* ref2 = (const float*)d_in[7];
  const float* ref3 = (const float*)d_in[8];
  float* out = (float*)d_out;
  float* ws = (float*)d_ws;

  const int B = 2;
  size_t off_planes = 0;
  size_t off_r2n = off_planes + (size_t)B * 4096 * 576 * 2; // 4 half-planes
  size_t off_l2n = off_r2n + (size_t)B * 1024 * 1152;
  size_t off_r1n = off_l2n + (size_t)B * 1152 * 1024;
  size_t off_l1n = off_r1n + (size_t)B * 256 * 2304;
  size_t off_R2  = off_l1n + (size_t)B * 2304 * 256;
  size_t off_R1  = off_R2  + (size_t)B * 1024 * 1024;
  size_t off_up2 = off_R1  + (size_t)B * 256 * 256;     // [2,4096,1024]
  size_t off_up1 = off_up2 + (size_t)B * 4096 * 1024;   // [2,4096,256]
  size_t off_S   = off_up1 + (size_t)B * 4096 * 256;    // 21504 floats (all levels)
  size_t off_invn= off_S   + 21504;                     // 21504 floats
  size_t off_pk  = off_invn+ 21504;                     // [2,4096] u64
  size_t off_arg = off_pk  + (size_t)B * 4096 * 2;      // [2,4096] int

  const size_t PLANE = (size_t)B * 4096 * 576;
  _Float16* r3hi = (_Float16*)(ws + off_planes);
  _Float16* r3lo = r3hi + PLANE;
  _Float16* l3hi = r3lo + PLANE;
  _Float16* l3lo = l3hi + PLANE;

  unsigned long long* pk = (unsigned long long*)(ws + off_pk);
  int* argp = (int*)(ws + off_arg);

  // 1. zero R1 accumulators + packed buffer
  init_multi<<<288, 256, 0, stream>>>((unsigned long long*)(ws + off_R1), pk);
  // 2-3. norms for all 6 descriptor inputs
  sumsq_multi<<<84, 256, 0, stream>>>(refsr3, lrsr3, refsr2, lrsr2, refsr1, lrsr1,
                                      ws + off_S);
  invnorm_multi<<<84, 256, 0, stream>>>(ws + off_S, ws + off_invn);
  // 4-6. descriptors
  desc_split_multi<<<4096, 256, 0, stream>>>(refsr3, lrsr3, r3hi, r3lo, l3hi, l3lo,
                                             ws + off_invn);
  desc_l_multi<<<13824, 256, 0, stream>>>(lrsr2, lrsr1, ws + off_l2n, ws + off_l1n,
                                          ws + off_invn);
  desc_r_multi<<<13824, 256, 0, stream>>>(refsr2, refsr1, ws + off_r2n, ws + off_r1n,
                                          ws + off_invn);
  // 7-8. small correlation GEMMs
  {
    dim3 g(1024 / 64, 1024 / 64, B);
    gemm64_kernel<<<g, 256, 0, stream>>>(ws + off_r2n, ws + off_l2n, ws + off_R2,
                                         1024, 1024, 1152);
  }
  {
    dim3 g(256 / 64, 256 / 64, B * 8);
    gemm64sk_kernel<<<g, 256, 0, stream>>>(ws + off_r1n, ws + off_l1n, ws + off_R1,
                                           256, 256, 2304, 8);
  }
  // 9. both bicubic row-upsamples
  upsample_multi<<<40960, 256, 0, stream>>>(ws + off_R2, ws + off_R1,
                                            ws + off_up2, ws + off_up1);
  // 10. fused R3 MFMA GEMM + bicubic add + max/argmax
  {
    dim3 g(4096 / 128, 4096 / 128, B);
    mfma_fused_kernel<<<g, 256, 0, stream>>>(r3hi, r3lo, l3hi, l3lo,
                                             ws + off_up2, ws + off_up1, pk);
  }
  // 11. unpack S_3 / argmax
  finalize_kernel<<<DIVUP(B * 4096, 256), 256, 0, stream>>>(pk, out, argp, B * 4096);

  // 12. batched channel-last transposes of ref1/2/3 into dead ws regions
  // (planes + up2 are dead after mfma_fused)
  float* refT3 = ws + off_planes;                 // 2,097,152 floats
  float* refT2 = refT3 + (size_t)2 * 256 * 4096;  // 4,194,304 floats (in planes)
  float* refT1 = ws + off_up2;                    // 8,388,608 floats (exact fit)
  transpose_multi<<<14336, 256, 0, stream>>>(ref3, ref2, ref1, refT3, refT2, refT1);

  // 13-15. fold-gathers with fused channel-first store
  float* T3 = out + 8192;
  float* T2 = T3 + (size_t)B * 256 * 64 * 64;
  float* T1 = T2 + (size_t)B * 128 * 128 * 128;
  {
    dim3 g(64 / 16, 64, B);
    foldT_kernel<3, 1, 1, 8, 6><<<g, 256, 0, stream>>>(refT3, argp, T3);
  }
  {
    dim3 g(128 / 16, 128, B);
    foldT_kernel<6, 2, 2, 7, 7><<<g, 256, 0, stream>>>(refT2, argp, T2);
  }
  {
    dim3 g(256 / 16, 256, B);
    foldT_kernel<12, 4, 4, 6, 8><<<g, 256, 0, stream>>>(refT1, argp, T1);
  }
}

// Round 9
// 639.526 us; speedup vs baseline: 2.4014x; 1.0383x over previous
//
#include <hip/hip_runtime.h>
#include <cstdint>

#define DIVUP(a,b) (((a)+(b)-1)/(b))

typedef __attribute__((ext_vector_type(4))) float f32x4;
typedef __attribute__((ext_vector_type(8))) _Float16 half8;

// Direct global->LDS DMA, 16B per lane. LDS dest is WAVE-UNIFORM base + lane*16.
__device__ __forceinline__ void gload_lds16(const void* g, void* l) {
  __builtin_amdgcn_global_load_lds(
      (const __attribute__((address_space(1))) void*)g,
      (__attribute__((address_space(3))) void*)l, 16, 0, 0);
}

__device__ __forceinline__ float cubicw(float x) {
  // PyTorch bicubic kernel, a = -0.75
  float ax = fabsf(x);
  float ax2 = ax * ax;
  float ax3 = ax2 * ax;
  if (ax <= 1.0f) return 1.25f * ax3 - 2.25f * ax2 + 1.0f;
  if (ax < 2.0f)  return -0.75f * ax3 + 3.75f * ax2 - 6.0f * ax + 3.0f;
  return 0.0f;
}

// ---------------- multi-job S = per-pixel channel sumsq ----------------
// jobs: [0,32) refsr3 C64 HW4096 so=0 | [32,64) lrsr3 so=8192 |
// [64,72) refsr2 C128 HW1024 so=16384 | [72,80) lrsr2 so=18432 |
// [80,82) refsr1 C256 HW256 so=20480 | [82,84) lrsr1 so=20992
__global__ void sumsq_multi(const float* __restrict__ r3, const float* __restrict__ l3,
                            const float* __restrict__ r2, const float* __restrict__ l2,
                            const float* __restrict__ r1, const float* __restrict__ l1,
                            float* __restrict__ S) {
  int blk = blockIdx.x;
  const float* x; int C, HW, so, base;
  if (blk < 32)      { x = r3; C = 64;  HW = 4096; so = 0;     base = 0;  }
  else if (blk < 64) { x = l3; C = 64;  HW = 4096; so = 8192;  base = 32; }
  else if (blk < 72) { x = r2; C = 128; HW = 1024; so = 16384; base = 64; }
  else if (blk < 80) { x = l2; C = 128; HW = 1024; so = 18432; base = 72; }
  else if (blk < 82) { x = r1; C = 256; HW = 256;  so = 20480; base = 80; }
  else               { x = l1; C = 256; HW = 256;  so = 20992; base = 82; }
  int i = (blk - base) * 256 + threadIdx.x;
  if (i >= 2 * HW) return;
  int pix = i % HW, b = i / HW;
  const float* p = x + (size_t)b * C * HW + pix;
  float s = 0.f;
  for (int c = 0; c < C; ++c) { float v = p[(size_t)c * HW]; s += v * v; }
  S[so + i] = s;
}

// ---------------- multi-job invn = 1/max(sqrt(3x3 sum of S),1e-12) ------
__global__ void invnorm_multi(const float* __restrict__ S, float* __restrict__ invn) {
  int blk = blockIdx.x;
  int H, so, base;
  if (blk < 32)      { H = 64; so = 0;     base = 0;  }
  else if (blk < 64) { H = 64; so = 8192;  base = 32; }
  else if (blk < 72) { H = 32; so = 16384; base = 64; }
  else if (blk < 80) { H = 32; so = 18432; base = 72; }
  else if (blk < 82) { H = 16; so = 20480; base = 80; }
  else               { H = 16; so = 20992; base = 82; }
  int W = H;
  int i = (blk - base) * 256 + threadIdx.x;
  if (i >= 2 * H * W) return;
  int p = i % (H * W), b = i / (H * W);
  int ph = p / W, pw = p % W;
  const float* Sb = S + so + (size_t)b * H * W;
  float s = 0.f;
  for (int ki = 0; ki < 3; ++ki) {
    int y = ph + ki - 1;
    if (y < 0 || y >= H) continue;
    for (int kj = 0; kj < 3; ++kj) {
      int xx = pw + kj - 1;
      if (xx < 0 || xx >= W) continue;
      s += Sb[y * W + xx];
    }
  }
  float n = fmaxf(sqrtf(s), 1e-12f);
  invn[so + i] = 1.0f / n;
}

// ------------- multi-job split-f16 descriptors (levels 3 AND 2) ----------
// Pixel-major [b][p][c*9+r] halves. jobs:
// [0,2048)    refsr3 C64  HW4096 io=0     -> r3hi/r3lo
// [2048,4096) lrsr3  C64  HW4096 io=8192  -> l3hi/l3lo
// [4096,5120) refsr2 C128 HW1024 io=16384 -> r2hi/r2lo
// [5120,6144) lrsr2  C128 HW1024 io=18432 -> l2hi/l2lo
__global__ void desc_split_multi(const float* __restrict__ r3, const float* __restrict__ l3,
                                 const float* __restrict__ r2, const float* __restrict__ l2,
                                 _Float16* __restrict__ r3hi, _Float16* __restrict__ r3lo,
                                 _Float16* __restrict__ l3hi, _Float16* __restrict__ l3lo,
                                 _Float16* __restrict__ r2hi, _Float16* __restrict__ r2lo,
                                 _Float16* __restrict__ l2hi, _Float16* __restrict__ l2lo,
                                 const float* __restrict__ invn) {
  int blk = blockIdx.x;
  const float* x; _Float16* hi; _Float16* lo; int C, H, io, base;
  if (blk < 2048)      { x = r3; hi = r3hi; lo = r3lo; C = 64;  H = 64; io = 0;     base = 0; }
  else if (blk < 4096) { x = l3; hi = l3hi; lo = l3lo; C = 64;  H = 64; io = 8192;  base = 2048; }
  else if (blk < 5120) { x = r2; hi = r2hi; lo = r2lo; C = 128; H = 32; io = 16384; base = 4096; }
  else                 { x = l2; hi = l2hi; lo = l2lo; C = 128; H = 32; io = 18432; base = 5120; }
  int W = H, HW = H * W;
  int i = (blk - base) * 256 + threadIdx.x;
  if (i >= 2 * C * HW) return;
  int c = i % C;
  int p = (i / C) % HW;
  int b = i / (C * HW);
  int ph = p / W, pw = p % W;
  float s = invn[io + b * HW + p];
  size_t obase = ((size_t)b * HW + p) * (size_t)(C * 9) + (size_t)c * 9;
  const float* xb = x + (size_t)(b * C + c) * HW;
#pragma unroll
  for (int r = 0; r < 9; ++r) {
    int y = ph + r / 3 - 1, xx = pw + r % 3 - 1;
    float v = 0.f;
    if (y >= 0 && y < H && xx >= 0 && xx < W) v = xb[y * W + xx] * s;
    _Float16 h = (_Float16)v;
    float hf = (float)h;
    _Float16 l = (_Float16)((v - hf) * 4096.0f);
    hi[obase + r] = h;
    lo[obase + r] = l;
  }
}

// ---------------- level-1 fp32 descriptors (for the tiny R1 GEMM) --------
__global__ void desc_l1_kernel(const float* __restrict__ x, float* __restrict__ out,
                               const float* __restrict__ invn) {
  const int C = 256, H = 16, W = 16, HW = 256, D = 2304, io = 20992;
  int i = blockIdx.x * 256 + threadIdx.x;
  if (i >= 2 * D * HW) return;
  int p = i % HW;
  int d = (i / HW) % D;
  int b = i / (HW * D);
  int c = d / 9, r = d % 9, ki = r / 3, kj = r % 3;
  int ph = p / W, pw = p % W;
  int y = ph + ki - 1, xx = pw + kj - 1;
  float v = 0.f;
  if (y >= 0 && y < H && xx >= 0 && xx < W) v = x[((size_t)(b * C + c) * H + y) * W + xx];
  out[i] = v * invn[io + b * HW + p];
}

__global__ void desc_r1_kernel(const float* __restrict__ x, float* __restrict__ out,
                               const float* __restrict__ invn) {
  const int C = 256, H = 16, W = 16, HW = 256, D = 2304, io = 20480;
  int i = blockIdx.x * 256 + threadIdx.x;
  if (i >= 2 * D * HW) return;
  int d = i % D;
  int p = (i / D) % HW;
  int b = i / (D * HW);
  int c = d / 9, r = d % 9, ki = r / 3, kj = r % 3;
  int ph = p / W, pw = p % W;
  int y = ph + ki - 1, xx = pw + kj - 1;
  float v = 0.f;
  if (y >= 0 && y < H && xx >= 0 && xx < W) v = x[((size_t)(b * C + c) * H + y) * W + xx];
  out[i] = v * invn[io + b * HW + p];
}

// ---------------- multi-job axis-1 bicubic upsample to 4096 rows --------
__global__ void upsample_multi(const float* __restrict__ R2, const float* __restrict__ R1,
                               float* __restrict__ up2, float* __restrict__ up1) {
  int blk = blockIdx.x;
  const float* Rin; float* out; int Nin, cols, base; float invscale;
  if (blk < 32768) { Rin = R2; out = up2; Nin = 1024; cols = 1024; invscale = 0.25f;   base = 0; }
  else             { Rin = R1; out = up1; Nin = 256;  cols = 256;  invscale = 0.0625f; base = 32768; }
  int i = (blk - base) * 256 + threadIdx.x;
  if (i >= 2 * 4096 * cols) return;
  int j = i % cols;
  int n = (i / cols) & 4095;
  int b = i / (cols * 4096);
  float src = (n + 0.5f) * invscale - 0.5f;
  float f = floorf(src);
  float tt = src - f;
  int fi = (int)f;
  const float* Rb = Rin + (size_t)b * Nin * cols;
  float s = 0.f;
#pragma unroll
  for (int tp = 0; tp < 4; ++tp) {
    int ii = min(max(fi + tp - 1, 0), Nin - 1);
    s += cubicw(tt - (float)(tp - 1)) * Rb[(size_t)ii * cols + j];
  }
  out[i] = s;
}

// zero R1 (65536 u64) + packed (8192 u64) in one dispatch
__global__ void init_multi(unsigned long long* __restrict__ R1z,
                           unsigned long long* __restrict__ pk) {
  int i = blockIdx.x * blockDim.x + threadIdx.x;
  if (i < 65536) R1z[i] = 0ull;
  else if (i < 65536 + 8192) pk[i - 65536] = 0ull;
}

// Split-K fp32 GEMM with atomicAdd epilogue (tiny R1 GEMM; SK=8 -> 256 blocks).
__global__ __launch_bounds__(256)
void gemm64sk_kernel(const float* __restrict__ A, const float* __restrict__ B,
                     float* __restrict__ C, int M, int N, int K, int SK) {
  int zz = blockIdx.z;
  int b = zz / SK, kc = zz % SK;
  int kchunk = K / SK;
  int kbeg = kc * kchunk, kend = kbeg + kchunk;
  const float* Ab = A + (size_t)b * M * K;
  const float* Bb = B + (size_t)b * K * N;
  __shared__ float As[16][68];
  __shared__ float Bs[16][64];
  int row0 = blockIdx.y * 64;
  int col0 = blockIdx.x * 64;
  int t = threadIdx.x;
  int tx = t & 15, ty = t >> 4;
  float acc[4][4] = {};
  int la_r = t >> 2;
  int la_k = (t & 3) << 2;
  int lb_r = t >> 4;
  int lb_c = (t & 15) << 2;
  const float* Aptr = Ab + (size_t)(row0 + la_r) * K + la_k;
  const float* Bptr = Bb + (size_t)lb_r * N + col0 + lb_c;
  float4 av = *(const float4*)(Aptr + kbeg);
  float4 bv = *(const float4*)(Bptr + (size_t)kbeg * N);
  for (int k0 = kbeg; k0 < kend; k0 += 16) {
    __syncthreads();
    As[la_k + 0][la_r] = av.x;
    As[la_k + 1][la_r] = av.y;
    As[la_k + 2][la_r] = av.z;
    As[la_k + 3][la_r] = av.w;
    *(float4*)&Bs[lb_r][lb_c] = bv;
    __syncthreads();
    if (k0 + 16 < kend) {
      av = *(const float4*)(Aptr + k0 + 16);
      bv = *(const float4*)(Bptr + (size_t)(k0 + 16) * N);
    }
#pragma unroll
    for (int k = 0; k < 16; ++k) {
      float4 a = *(const float4*)&As[k][ty << 2];
      float4 bq = *(const float4*)&Bs[k][tx << 2];
      float av4[4] = {a.x, a.y, a.z, a.w};
      float bv4[4] = {bq.x, bq.y, bq.z, bq.w};
#pragma unroll
      for (int ii = 0; ii < 4; ++ii)
#pragma unroll
        for (int jj = 0; jj < 4; ++jj)
          acc[ii][jj] = fmaf(av4[ii], bv4[jj], acc[ii][jj]);
    }
  }
  float* Cb = C + (size_t)b * M * N;
#pragma unroll
  for (int ii = 0; ii < 4; ++ii)
#pragma unroll
    for (int jj = 0; jj < 4; ++jj)
      atomicAdd(&Cb[(size_t)(row0 + (ty << 2) + ii) * N + col0 + (tx << 2) + jj],
                acc[ii][jj]);
}

// ---- R2 split-f16 MFMA GEMM: clone of mfma_fused's PROVEN main loop with
// K=1152, plain fp32 C-store epilogue. Separate function so mfma_fused's
// fragile register allocation is untouched.
__global__ __launch_bounds__(256, 2)
void mfma_r2_kernel(const _Float16* __restrict__ Ahi, const _Float16* __restrict__ Alo,
                    const _Float16* __restrict__ Bhi, const _Float16* __restrict__ Blo,
                    float* __restrict__ Cout) {
  const int K = 1152;
  int bx = blockIdx.x, by = blockIdx.y, b = blockIdx.z;
  int row0 = by * 128;
  int col0 = bx * 128;
  int t = threadIdx.x;
  int lane = t & 63, wave = t >> 6;
  int wy = wave & 1, wx = wave >> 1;
  int quad = lane >> 4, lm = lane & 15;

  __shared__ _Float16 lds[2 * 4 * 4096];

  int off[2];
#pragma unroll
  for (int h = 0; h < 2; ++h) {
    int d = wave * 128 + h * 64 + lane;
    int line = d >> 3;
    int c3 = (d & 7) ^ (line & 7);
    int row = (line << 1) | (c3 >> 2);
    int c = c3 & 3;
    off[h] = row * (K * 2) + c * 16;
  }
  const char* pg[4];
  pg[0] = (const char*)Ahi + ((size_t)b * 1024 + row0) * (size_t)K * 2;
  pg[1] = (const char*)Alo + ((size_t)b * 1024 + row0) * (size_t)K * 2;
  pg[2] = (const char*)Bhi + ((size_t)b * 1024 + col0) * (size_t)K * 2;
  pg[3] = (const char*)Blo + ((size_t)b * 1024 + col0) * (size_t)K * 2;

  int ra[4], rb[4];
#pragma unroll
  for (int i = 0; i < 4; ++i) {
    int rowa = wy * 64 + i * 16 + lm;
    int la_ = rowa >> 1;
    ra[i] = la_ * 128 + (((((rowa & 1) << 2) | quad) ^ (la_ & 7)) << 4);
    int rowb = wx * 64 + i * 16 + lm;
    int lb_ = rowb >> 1;
    rb[i] = lb_ * 128 + (((((rowb & 1) << 2) | quad) ^ (lb_ & 7)) << 4);
  }

  f32x4 S1[4][4] = {};
  f32x4 S2[4][4] = {};

#pragma unroll
  for (int p = 0; p < 4; ++p) {
    char* lb_ = (char*)lds + p * 8192 + wave * 2048;
    gload_lds16(pg[p] + off[0], lb_);
    gload_lds16(pg[p] + off[1], lb_ + 1024);
  }
  __syncthreads();

  int buf = 0;
  for (int tki = 0; tki < 36; ++tki) {
    const char* lb = (const char*)lds + buf * 32768;
    half8 aH[4], aL[4], bH[4], bL[4];
#pragma unroll
    for (int i = 0; i < 4; ++i) {
      aH[i] = *(const half8*)(lb + ra[i]);
      aL[i] = *(const half8*)(lb + 8192 + ra[i]);
      bH[i] = *(const half8*)(lb + 16384 + rb[i]);
      bL[i] = *(const half8*)(lb + 24576 + rb[i]);
    }
    if (tki < 35) {
      int kbyte = (tki + 1) * 64;
#pragma unroll
      for (int p = 0; p < 4; ++p) {
        char* lw = (char*)lds + (buf ^ 1) * 32768 + p * 8192 + wave * 2048;
        gload_lds16(pg[p] + kbyte + off[0], lw);
        gload_lds16(pg[p] + kbyte + off[1], lw + 1024);
      }
    }
#pragma unroll
    for (int i = 0; i < 4; ++i)
#pragma unroll
      for (int j = 0; j < 4; ++j) {
        S1[i][j] = __builtin_amdgcn_mfma_f32_16x16x32_f16(aH[i], bH[j], S1[i][j], 0, 0, 0);
        S2[i][j] = __builtin_amdgcn_mfma_f32_16x16x32_f16(aH[i], bL[j], S2[i][j], 0, 0, 0);
        S2[i][j] = __builtin_amdgcn_mfma_f32_16x16x32_f16(aL[i], bH[j], S2[i][j], 0, 0, 0);
      }
    __syncthreads();
    buf ^= 1;
  }

  const float inv4096 = 1.0f / 4096.0f;
  float* Cb = Cout + (size_t)b * 1024 * 1024;
#pragma unroll
  for (int i = 0; i < 4; ++i)
#pragma unroll
    for (int j = 0; j < 4; ++j)
#pragma unroll
      for (int r = 0; r < 4; ++r) {
        int gn = row0 + wy * 64 + i * 16 + quad * 4 + r;
        int gm = col0 + wx * 64 + j * 16 + lm;
        Cb[(size_t)gn * 1024 + gm] = S1[i][j][r] + S2[i][j][r] * inv4096;
      }
}

// MFMA split-f16 GEMM — EXACT R1 kernel (184us, MfmaUtil 27.5%). DO NOT TOUCH:
// epilogue restructures spill the K-loop accumulators (R2/R3: 650-700us, 1GB
// of scratch writes). Verified restored in R4/R5.
__global__ __launch_bounds__(256, 2)
void mfma_fused_kernel(const _Float16* __restrict__ Ahi, const _Float16* __restrict__ Alo,
                       const _Float16* __restrict__ Bhi, const _Float16* __restrict__ Blo,
                       const float* __restrict__ up2, const float* __restrict__ up1,
                       unsigned long long* __restrict__ packed) {
  const int K = 576;
  int bid = (blockIdx.z * 32 + blockIdx.y) * 32 + blockIdx.x;
  int swz = (bid & 7) * 256 + (bid >> 3);
  int bx = swz & 31;
  int by = (swz >> 5) & 31;
  int b  = swz >> 10;

  int row0 = by * 128;
  int col0 = bx * 128;
  int t = threadIdx.x;
  int lane = t & 63, wave = t >> 6;
  int wy = wave & 1, wx = wave >> 1;
  int quad = lane >> 4, lm = lane & 15;

  __shared__ _Float16 lds[2 * 4 * 4096];

  int off[2];
#pragma unroll
  for (int h = 0; h < 2; ++h) {
    int d = wave * 128 + h * 64 + lane;
    int line = d >> 3;
    int c3 = (d & 7) ^ (line & 7);
    int row = (line << 1) | (c3 >> 2);
    int c = c3 & 3;
    off[h] = row * (K * 2) + c * 16;
  }
  const char* pg[4];
  pg[0] = (const char*)Ahi + ((size_t)b * 4096 + row0) * (size_t)K * 2;
  pg[1] = (const char*)Alo + ((size_t)b * 4096 + row0) * (size_t)K * 2;
  pg[2] = (const char*)Bhi + ((size_t)b * 4096 + col0) * (size_t)K * 2;
  pg[3] = (const char*)Blo + ((size_t)b * 4096 + col0) * (size_t)K * 2;

  int ra[4], rb[4];
#pragma unroll
  for (int i = 0; i < 4; ++i) {
    int rowa = wy * 64 + i * 16 + lm;
    int la_ = rowa >> 1;
    ra[i] = la_ * 128 + (((((rowa & 1) << 2) | quad) ^ (la_ & 7)) << 4);
    int rowb = wx * 64 + i * 16 + lm;
    int lb_ = rowb >> 1;
    rb[i] = lb_ * 128 + (((((rowb & 1) << 2) | quad) ^ (lb_ & 7)) << 4);
  }

  f32x4 S1[4][4] = {};
  f32x4 S2[4][4] = {};

#pragma unroll
  for (int p = 0; p < 4; ++p) {
    char* lb_ = (char*)lds + p * 8192 + wave * 2048;
    gload_lds16(pg[p] + off[0], lb_);
    gload_lds16(pg[p] + off[1], lb_ + 1024);
  }
  __syncthreads();

  int buf = 0;
  for (int t18 = 0; t18 < 18; ++t18) {
    const char* lb = (const char*)lds + buf * 32768;
    half8 aH[4], aL[4], bH[4], bL[4];
#pragma unroll
    for (int i = 0; i < 4; ++i) {
      aH[i] = *(const half8*)(lb + ra[i]);
      aL[i] = *(const half8*)(lb + 8192 + ra[i]);
      bH[i] = *(const half8*)(lb + 16384 + rb[i]);
      bL[i] = *(const half8*)(lb + 24576 + rb[i]);
    }
    if (t18 < 17) {
      int kbyte = (t18 + 1) * 64;
#pragma unroll
      for (int p = 0; p < 4; ++p) {
        char* lw = (char*)lds + (buf ^ 1) * 32768 + p * 8192 + wave * 2048;
        gload_lds16(pg[p] + kbyte + off[0], lw);
        gload_lds16(pg[p] + kbyte + off[1], lw + 1024);
      }
    }
#pragma unroll
    for (int i = 0; i < 4; ++i)
#pragma unroll
      for (int j = 0; j < 4; ++j) {
        S1[i][j] = __builtin_amdgcn_mfma_f32_16x16x32_f16(aH[i], bH[j], S1[i][j], 0, 0, 0);
        S2[i][j] = __builtin_amdgcn_mfma_f32_16x16x32_f16(aH[i], bL[j], S2[i][j], 0, 0, 0);
        S2[i][j] = __builtin_amdgcn_mfma_f32_16x16x32_f16(aL[i], bH[j], S2[i][j], 0, 0, 0);
      }
    __syncthreads();
    buf ^= 1;
  }

  const float inv4096 = 1.0f / 4096.0f;
  const float* u2b = up2 + (size_t)b * 4096 * 1024;
  const float* u1b = up1 + (size_t)b * 4096 * 256;
#pragma unroll
  for (int j = 0; j < 4; ++j) {
    int gm = col0 + wx * 64 + j * 16 + lm;
    float src2 = (gm + 0.5f) * 0.25f - 0.5f;
    float f2 = floorf(src2); float t2 = src2 - f2; int i2 = (int)f2;
    int idx2[4]; float w2[4];
#pragma unroll
    for (int tp = 0; tp < 4; ++tp) {
      idx2[tp] = min(max(i2 + tp - 1, 0), 1023);
      w2[tp] = cubicw(t2 - (float)(tp - 1));
    }
    float src1 = (gm + 0.5f) * 0.0625f - 0.5f;
    float f1 = floorf(src1); float t1 = src1 - f1; int i1 = (int)f1;
    int idx1[4]; float w1[4];
#pragma unroll
    for (int tp = 0; tp < 4; ++tp) {
      idx1[tp] = min(max(i1 + tp - 1, 0), 255);
      w1[tp] = cubicw(t1 - (float)(tp - 1));
    }
    unsigned long long best = 0ull;
#pragma unroll
    for (int i = 0; i < 4; ++i) {
#pragma unroll
      for (int r = 0; r < 4; ++r) {
        int gn = row0 + wy * 64 + i * 16 + quad * 4 + r;
        float v = S1[i][j][r] + S2[i][j][r] * inv4096;
        const float* r2row = u2b + (size_t)gn * 1024;
        const float* r1row = u1b + (size_t)gn * 256;
        v += w2[0] * r2row[idx2[0]] + w2[1] * r2row[idx2[1]]
           + w2[2] * r2row[idx2[2]] + w2[3] * r2row[idx2[3]];
        v += w1[0] * r1row[idx1[0]] + w1[1] * r1row[idx1[1]]
           + w1[2] * r1row[idx1[2]] + w1[3] * r1row[idx1[3]];
        v *= (1.0f / 3.0f);
        unsigned int fb = __float_as_uint(v);
        unsigned int key = (fb & 0x80000000u) ? ~fb : (fb | 0x80000000u);
        unsigned long long pk = ((unsigned long long)key << 32)
                              | (unsigned long long)(0xFFFFFFFFu - (unsigned)gn);
        best = best > pk ? best : pk;
      }
    }
    unsigned long long o;
    o = __shfl_xor(best, 16); best = best > o ? best : o;
    o = __shfl_xor(best, 32); best = best > o ? best : o;
    if (lane < 16) atomicMax(&packed[(size_t)b * 4096 + gm], best);
  }
}

__global__ void finalize_kernel(const unsigned long long* __restrict__ packed,
                                float* __restrict__ s3_out, int* __restrict__ arg, int total) {
  int i = blockIdx.x * blockDim.x + threadIdx.x;
  if (i >= total) return;
  unsigned long long pk = packed[i];
  unsigned int key = (unsigned int)(pk >> 32);
  unsigned int fb = (key & 0x80000000u) ? (key ^ 0x80000000u) : ~key;
  s3_out[i] = __uint_as_float(fb);
  arg[i] = (int)(0xFFFFFFFFu - (unsigned int)(pk & 0xFFFFFFFFull));
}

// ------------- batched multi-job 2D transpose (3 ref levels) -------------
__global__ __launch_bounds__(256)
void transpose_multi(const float* __restrict__ ref3, const float* __restrict__ ref2,
                     const float* __restrict__ ref1, float* __restrict__ o3,
                     float* __restrict__ o2, float* __restrict__ o1) {
  __shared__ float tile[32][33];
  int blk = blockIdx.x;
  const float* in; float* out; int R, S, gx, gy, base;
  if (blk < 2048)      { in = ref3; out = o3; R = 256; S = 4096;  gx = 128;  gy = 8; base = 0; }
  else if (blk < 6144) { in = ref2; out = o2; R = 128; S = 16384; gx = 512;  gy = 4; base = 2048; }
  else                 { in = ref1; out = o1; R = 64;  S = 65536; gx = 2048; gy = 2; base = 6144; }
  int local = blk - base;
  int pb = gx * gy;
  int b = local / pb;
  int rem = local % pb;
  int r0 = (rem / gx) * 32;
  int s0 = (rem % gx) * 32;
  int tx = threadIdx.x & 31, ty = threadIdx.x >> 5;
  const float* ib = in + (size_t)b * R * S;
  float* ob = out + (size_t)b * R * S;
#pragma unroll
  for (int k = 0; k < 4; ++k)
    tile[ty + 8 * k][tx] = ib[(size_t)(r0 + ty + 8 * k) * S + s0 + tx];
  __syncthreads();
#pragma unroll
  for (int k = 0; k < 4; ++k)
    ob[(size_t)(s0 + ty + 8 * k) * R + r0 + tx] = tile[tx][ty + 8 * k];
}

// ---- fold-gather body: channel-last float4 reads + fused channel-first store
template<int KK, int SS, int PP, int CL2, int WL2>
__device__ __forceinline__ void foldT_body(const float* __restrict__ refT,
                                           const int* __restrict__ arg,
                                           float* __restrict__ outCF,
                                           float* lds, int bx, int h, int b) {
  const int C = 1 << CL2, W = 1 << WL2;
  const int NK = (C / 4) / 16;
  int tid = threadIdx.x;
  int pl = tid >> 4, c4g = tid & 15;
  int w0 = bx * 16;
  int w = w0 + pl;
  int y = h + PP, x = w + PP;
  int ho_lo = (y - KK + 1) > 0 ? (y - KK + 1 + SS - 1) / SS : 0;
  int ho_hi = min(63, y / SS);
  int wo_lo = (x - KK + 1) > 0 ? (x - KK + 1 + SS - 1) / SS : 0;
  int wo_hi = min(63, x / SS);
  const int* argb = arg + b * 4096;
  const f32x4* refb4 = (const f32x4*)(refT + ((size_t)b << (2 * WL2 + CL2)));
  f32x4 acc[NK] = {};
  for (int ho = ho_lo; ho <= ho_hi; ++ho) {
    int ki = y - SS * ho;
    for (int wo = wo_lo; wo <= wo_hi; ++wo) {
      int kj = x - SS * wo;
      int q = argb[(ho << 6) + wo];
      int qh = q >> 6, qw = q & 63;
      int ry = SS * qh + ki - PP;
      int rx = SS * qw + kj - PP;
      if (ry >= 0 && ry < W && rx >= 0 && rx < W) {
        const f32x4* pb4 = refb4 + (((size_t)(ry << WL2) + rx) << (CL2 - 2));
#pragma unroll
        for (int k = 0; k < NK; ++k) acc[k] += pb4[c4g + k * 16];
      }
    }
  }
#pragma unroll
  for (int k = 0; k < NK; ++k) {
    int c4 = c4g + k * 16;
#pragma unroll
    for (int j = 0; j < 4; ++j)
      lds[(4 * c4 + j) * 17 + pl] = acc[k][j] * (1.0f / 9.0f);
  }
  __syncthreads();
  size_t ob = ((size_t)(b * C)) << (2 * WL2);
  for (int idx = tid; idx < C * 16; idx += 256) {
    int c = idx >> 4, j = idx & 15;
    outCF[ob + ((size_t)c << (2 * WL2)) + (h << WL2) + w0 + j] = lds[c * 17 + j];
  }
}

// one dispatch for all three fold levels:
// [0,512) T3 ; [512,2560) T2 ; [2560,10752) T1
__global__ __launch_bounds__(256)
void foldT_all(const float* __restrict__ refT3, const float* __restrict__ refT2,
               const float* __restrict__ refT1, const int* __restrict__ arg,
               float* __restrict__ T3, float* __restrict__ T2, float* __restrict__ T1) {
  __shared__ float lds[256 * 17];
  int blk = blockIdx.x;
  if (blk < 512) {
    int local = blk;
    foldT_body<3, 1, 1, 8, 6>(refT3, arg, T3, lds, local & 3, (local >> 2) & 63, local >> 8);
  } else if (blk < 2560) {
    int local = blk - 512;
    foldT_body<6, 2, 2, 7, 7>(refT2, arg, T2, lds, local & 7, (local >> 3) & 127, local >> 10);
  } else {
    int local = blk - 2560;
    foldT_body<12, 4, 4, 6, 8>(refT1, arg, T1, lds, local & 15, (local >> 4) & 255, local >> 12);
  }
}

extern "C" void kernel_launch(void* const* d_in, const int* in_sizes, int n_in,
                              void* d_out, int out_size, void* d_ws, size_t ws_size,
                              hipStream_t stream) {
  const float* lrsr1 = (const float*)d_in[0];
  const float* lrsr2 = (const float*)d_in[1];
  const float* lrsr3 = (const float*)d_in[2];
  const float* refsr1 = (const float*)d_in[3];
  const float* refsr2 = (const float*)d_in[4];
  const float* refsr3 = (const float*)d_in[5];
  const float* ref1 = (const float*)d_in[6];
  const float* ref2 = (const float*)d_in[7];
  const float* ref3 = (const float*)d_in[8];
  float* out = (float*)d_out;
  float* ws = (float*)d_ws;

  const int B = 2;
  size_t off_planes = 0;
  size_t off_pl2 = off_planes + (size_t)B * 4096 * 576 * 2; // 4 lvl3 half-planes
  // 4 lvl2 half-planes: 4 x (B*1024*1152 halves) = 2*B*1024*1152 FLOATS.
  // (R6 bug: reserved only half this -> desc_r1/l1 overwrote l2hi/l2lo -> NaN)
  size_t off_r1n = off_pl2 + (size_t)B * 1024 * 1152 * 2;
  size_t off_l1n = off_r1n + (size_t)B * 256 * 2304;
  size_t off_R2  = off_l1n + (size_t)B * 2304 * 256;
  size_t off_R1  = off_R2  + (size_t)B * 1024 * 1024;
  size_t off_up2 = off_R1  + (size_t)B * 256 * 256;     // [2,4096,1024]
  size_t off_up1 = off_up2 + (size_t)B * 4096 * 1024;   // [2,4096,256]
  size_t off_S   = off_up1 + (size_t)B * 4096 * 256;    // 21504 floats
  size_t off_invn= off_S   + 21504;                     // 21504 floats
  size_t off_pk  = off_invn+ 21504;                     // [2,4096] u64
  size_t off_arg = off_pk  + (size_t)B * 4096 * 2;      // [2,4096] int

  const size_t PLANE3 = (size_t)B * 4096 * 576;   // halves per lvl3 plane
  _Float16* r3hi = (_Float16*)(ws + off_planes);
  _Float16* r3lo = r3hi + PLANE3;
  _Float16* l3hi = r3lo + PLANE3;
  _Float16* l3lo = l3hi + PLANE3;
  const size_t PLANE2 = (size_t)B * 1024 * 1152;  // halves per lvl2 plane
  _Float16* r2hi = (_Float16*)(ws + off_pl2);
  _Float16* r2lo = r2hi + PLANE2;
  _Float16* l2hi = r2lo + PLANE2;
  _Float16* l2lo = l2hi + PLANE2;

  unsigned long long* pk = (unsigned long long*)(ws + off_pk);
  int* argp = (int*)(ws + off_arg);

  // 1. zero R1 accumulators + packed buffer
  init_multi<<<288, 256, 0, stream>>>((unsigned long long*)(ws + off_R1), pk);
  // 2-3. norms for all 6 descriptor inputs
  sumsq_multi<<<84, 256, 0, stream>>>(refsr3, lrsr3, refsr2, lrsr2, refsr1, lrsr1,
                                      ws + off_S);
  invnorm_multi<<<84, 256, 0, stream>>>(ws + off_S, ws + off_invn);
  // 4. split-f16 descriptors for levels 3 and 2 (pixel-major)
  desc_split_multi<<<6144, 256, 0, stream>>>(refsr3, lrsr3, refsr2, lrsr2,
                                             r3hi, r3lo, l3hi, l3lo,
                                             r2hi, r2lo, l2hi, l2lo,
                                             ws + off_invn);
  // 5-6. level-1 fp32 descriptors
  desc_l1_kernel<<<4608, 256, 0, stream>>>(lrsr1, ws + off_l1n, ws + off_invn);
  desc_r1_kernel<<<4608, 256, 0, stream>>>(refsr1, ws + off_r1n, ws + off_invn);
  // 7. R2 via split-f16 MFMA (was fp32 gemm64)
  {
    dim3 g(8, 8, B);
    mfma_r2_kernel<<<g, 256, 0, stream>>>(r2hi, r2lo, l2hi, l2lo, ws + off_R2);
  }
  // 8. R1 via fp32 split-K
  {
    dim3 g(256 / 64, 256 / 64, B * 8);
    gemm64sk_kernel<<<g, 256, 0, stream>>>(ws + off_r1n, ws + off_l1n, ws + off_R1,
                                           256, 256, 2304, 8);
  }
  // 9. both bicubic row-upsamples
  upsample_multi<<<40960, 256, 0, stream>>>(ws + off_R2, ws + off_R1,
                                            ws + off_up2, ws + off_up1);
  // 10. fused R3 MFMA GEMM + bicubic add + max/argmax
  {
    dim3 g(4096 / 128, 4096 / 128, B);
    mfma_fused_kernel<<<g, 256, 0, stream>>>(r3hi, r3lo, l3hi, l3lo,
                                             ws + off_up2, ws + off_up1, pk);
  }
  // 11. unpack S_3 / argmax
  finalize_kernel<<<DIVUP(B * 4096, 256), 256, 0, stream>>>(pk, out, argp, B * 4096);

  // 12. batched channel-last transposes of ref1/2/3 into dead ws regions
  float* refT3 = ws + off_planes;                 // 2,097,152 floats
  float* refT2 = refT3 + (size_t)2 * 256 * 4096;  // 4,194,304 floats
  float* refT1 = ws + off_up2;                    // 8,388,608 floats
  transpose_multi<<<14336, 256, 0, stream>>>(ref3, ref2, ref1, refT3, refT2, refT1);

  // 13. all three fold-gathers in one dispatch
  float* T3 = out + 8192;
  float* T2 = T3 + (size_t)B * 256 * 64 * 64;
  float* T1 = T2 + (size_t)B * 128 * 128 * 128;
  foldT_all<<<10752, 256, 0, stream>>>(refT3, refT2, refT1, argp, T3, T2, T1);
}

// Round 10
// 555.242 us; speedup vs baseline: 2.7660x; 1.1518x over previous
//
#include <hip/hip_runtime.h>
#include <cstdint>

#define DIVUP(a,b) (((a)+(b)-1)/(b))

typedef __attribute__((ext_vector_type(4))) float f32x4;
typedef __attribute__((ext_vector_type(8))) _Float16 half8;

// Direct global->LDS DMA, 16B per lane. LDS dest is WAVE-UNIFORM base + lane*16.
__device__ __forceinline__ void gload_lds16(const void* g, void* l) {
  __builtin_amdgcn_global_load_lds(
      (const __attribute__((address_space(1))) void*)g,
      (__attribute__((address_space(3))) void*)l, 16, 0, 0);
}

__device__ __forceinline__ float cubicw(float x) {
  // PyTorch bicubic kernel, a = -0.75
  float ax = fabsf(x);
  float ax2 = ax * ax;
  float ax3 = ax2 * ax;
  if (ax <= 1.0f) return 1.25f * ax3 - 2.25f * ax2 + 1.0f;
  if (ax < 2.0f)  return -0.75f * ax3 + 3.75f * ax2 - 6.0f * ax + 3.0f;
  return 0.0f;
}

// ---------------- multi-job S += partial channel sumsq (x8 c-slices) ----
// Base jobs (jb = blk>>3): [0,32) refsr3 C64 HW4096 so=0 | [32,64) lrsr3
// so=8192 | [64,72) refsr2 C128 HW1024 so=16384 | [72,80) lrsr2 so=18432 |
// [80,82) refsr1 C256 HW256 so=20480 | [82,84) lrsr1 so=20992.
// slice = blk&7 covers channels [slice*C/8,(slice+1)*C/8). S must be zeroed.
// (R9 diagnosis: 84 blocks = 0.3 waves/CU was pure latency exposure.)
__global__ void sumsq_multi(const float* __restrict__ r3, const float* __restrict__ l3,
                            const float* __restrict__ r2, const float* __restrict__ l2,
                            const float* __restrict__ r1, const float* __restrict__ l1,
                            float* __restrict__ S) {
  int blk = blockIdx.x;
  int slice = blk & 7;
  int jb = blk >> 3;
  const float* x; int C, HW, so, base;
  if (jb < 32)      { x = r3; C = 64;  HW = 4096; so = 0;     base = 0;  }
  else if (jb < 64) { x = l3; C = 64;  HW = 4096; so = 8192;  base = 32; }
  else if (jb < 72) { x = r2; C = 128; HW = 1024; so = 16384; base = 64; }
  else if (jb < 80) { x = l2; C = 128; HW = 1024; so = 18432; base = 72; }
  else if (jb < 82) { x = r1; C = 256; HW = 256;  so = 20480; base = 80; }
  else              { x = l1; C = 256; HW = 256;  so = 20992; base = 82; }
  int i = (jb - base) * 256 + threadIdx.x;
  if (i >= 2 * HW) return;
  int pix = i % HW, b = i / HW;
  int c0 = slice * (C >> 3), c1 = c0 + (C >> 3);
  const float* p = x + (size_t)b * C * HW + pix;
  float s = 0.f;
  for (int c = c0; c < c1; ++c) { float v = p[(size_t)c * HW]; s += v * v; }
  atomicAdd(&S[so + i], s);
}

// ---------------- multi-job invn = 1/max(sqrt(3x3 sum of S),1e-12) ------
__global__ void invnorm_multi(const float* __restrict__ S, float* __restrict__ invn) {
  int blk = blockIdx.x;
  int H, so, base;
  if (blk < 32)      { H = 64; so = 0;     base = 0;  }
  else if (blk < 64) { H = 64; so = 8192;  base = 32; }
  else if (blk < 72) { H = 32; so = 16384; base = 64; }
  else if (blk < 80) { H = 32; so = 18432; base = 72; }
  else if (blk < 82) { H = 16; so = 20480; base = 80; }
  else               { H = 16; so = 20992; base = 82; }
  int W = H;
  int i = (blk - base) * 256 + threadIdx.x;
  if (i >= 2 * H * W) return;
  int p = i % (H * W), b = i / (H * W);
  int ph = p / W, pw = p % W;
  const float* Sb = S + so + (size_t)b * H * W;
  float s = 0.f;
  for (int ki = 0; ki < 3; ++ki) {
    int y = ph + ki - 1;
    if (y < 0 || y >= H) continue;
    for (int kj = 0; kj < 3; ++kj) {
      int xx = pw + kj - 1;
      if (xx < 0 || xx >= W) continue;
      s += Sb[y * W + xx];
    }
  }
  float n = fmaxf(sqrtf(s), 1e-12f);
  invn[so + i] = 1.0f / n;
}

// ------------- multi-job split-f16 descriptors (levels 3 AND 2) ----------
// Pixel-major [b][p][c*9+r] halves. jobs:
// [0,2048)    refsr3 C64  HW4096 io=0     -> r3hi/r3lo
// [2048,4096) lrsr3  C64  HW4096 io=8192  -> l3hi/l3lo
// [4096,5120) refsr2 C128 HW1024 io=16384 -> r2hi/r2lo
// [5120,6144) lrsr2  C128 HW1024 io=18432 -> l2hi/l2lo
__global__ void desc_split_multi(const float* __restrict__ r3, const float* __restrict__ l3,
                                 const float* __restrict__ r2, const float* __restrict__ l2,
                                 _Float16* __restrict__ r3hi, _Float16* __restrict__ r3lo,
                                 _Float16* __restrict__ l3hi, _Float16* __restrict__ l3lo,
                                 _Float16* __restrict__ r2hi, _Float16* __restrict__ r2lo,
                                 _Float16* __restrict__ l2hi, _Float16* __restrict__ l2lo,
                                 const float* __restrict__ invn) {
  int blk = blockIdx.x;
  const float* x; _Float16* hi; _Float16* lo; int C, H, io, base;
  if (blk < 2048)      { x = r3; hi = r3hi; lo = r3lo; C = 64;  H = 64; io = 0;     base = 0; }
  else if (blk < 4096) { x = l3; hi = l3hi; lo = l3lo; C = 64;  H = 64; io = 8192;  base = 2048; }
  else if (blk < 5120) { x = r2; hi = r2hi; lo = r2lo; C = 128; H = 32; io = 16384; base = 4096; }
  else                 { x = l2; hi = l2hi; lo = l2lo; C = 128; H = 32; io = 18432; base = 5120; }
  int W = H, HW = H * W;
  int i = (blk - base) * 256 + threadIdx.x;
  if (i >= 2 * C * HW) return;
  int c = i % C;
  int p = (i / C) % HW;
  int b = i / (C * HW);
  int ph = p / W, pw = p % W;
  float s = invn[io + b * HW + p];
  size_t obase = ((size_t)b * HW + p) * (size_t)(C * 9) + (size_t)c * 9;
  const float* xb = x + (size_t)(b * C + c) * HW;
#pragma unroll
  for (int r = 0; r < 9; ++r) {
    int y = ph + r / 3 - 1, xx = pw + r % 3 - 1;
    float v = 0.f;
    if (y >= 0 && y < H && xx >= 0 && xx < W) v = xb[y * W + xx] * s;
    _Float16 h = (_Float16)v;
    float hf = (float)h;
    _Float16 l = (_Float16)((v - hf) * 4096.0f);
    hi[obase + r] = h;
    lo[obase + r] = l;
  }
}

// ------- level-1 fp32 descriptors, BOTH layouts in one dispatch ----------
// [0,4608) l-layout (lrsr1 -> l1n) ; [4608,9216) r-layout (refsr1 -> r1n)
__global__ void desc_f32_multi(const float* __restrict__ lin, const float* __restrict__ rin,
                               float* __restrict__ l1n, float* __restrict__ r1n,
                               const float* __restrict__ invn) {
  const int C = 256, H = 16, W = 16, HW = 256, D = 2304;
  int blk = blockIdx.x;
  bool rlay = blk >= 4608;
  const float* x = rlay ? rin : lin;
  float* out = rlay ? r1n : l1n;
  int io = rlay ? 20480 : 20992;
  int i = (rlay ? blk - 4608 : blk) * 256 + threadIdx.x;
  if (i >= 2 * D * HW) return;
  int p, d, b;
  if (rlay) { d = i % D; p = (i / D) % HW; b = i / (D * HW); }
  else      { p = i % HW; d = (i / HW) % D; b = i / (HW * D); }
  int c = d / 9, r = d % 9, ki = r / 3, kj = r % 3;
  int ph = p / W, pw = p % W;
  int y = ph + ki - 1, xx = pw + kj - 1;
  float v = 0.f;
  if (y >= 0 && y < H && xx >= 0 && xx < W) v = x[((size_t)(b * C + c) * H + y) * W + xx];
  out[i] = v * invn[io + b * HW + p];
}

// ---------------- multi-job axis-1 bicubic upsample to 4096 rows --------
__global__ void upsample_multi(const float* __restrict__ R2, const float* __restrict__ R1,
                               float* __restrict__ up2, float* __restrict__ up1) {
  int blk = blockIdx.x;
  const float* Rin; float* out; int Nin, cols, base; float invscale;
  if (blk < 32768) { Rin = R2; out = up2; Nin = 1024; cols = 1024; invscale = 0.25f;   base = 0; }
  else             { Rin = R1; out = up1; Nin = 256;  cols = 256;  invscale = 0.0625f; base = 32768; }
  int i = (blk - base) * 256 + threadIdx.x;
  if (i >= 2 * 4096 * cols) return;
  int j = i % cols;
  int n = (i / cols) & 4095;
  int b = i / (cols * 4096);
  float src = (n + 0.5f) * invscale - 0.5f;
  float f = floorf(src);
  float tt = src - f;
  int fi = (int)f;
  const float* Rb = Rin + (size_t)b * Nin * cols;
  float s = 0.f;
#pragma unroll
  for (int tp = 0; tp < 4; ++tp) {
    int ii = min(max(fi + tp - 1, 0), Nin - 1);
    s += cubicw(tt - (float)(tp - 1)) * Rb[(size_t)ii * cols + j];
  }
  out[i] = s;
}

// zero R1 (65536 u64) + packed (8192 u64) + R2 (1048576 u64) + S (21504 u64)
__global__ void init_multi(unsigned long long* __restrict__ R1z,
                           unsigned long long* __restrict__ pk,
                           unsigned long long* __restrict__ R2z,
                           unsigned long long* __restrict__ Sz) {
  int i = blockIdx.x * blockDim.x + threadIdx.x;
  if (i < 65536) R1z[i] = 0ull;
  else if (i < 65536 + 8192) pk[i - 65536] = 0ull;
  else if (i < 65536 + 8192 + 1048576) R2z[i - 65536 - 8192] = 0ull;
  else if (i < 65536 + 8192 + 1048576 + 21504) Sz[i - 65536 - 8192 - 1048576] = 0ull;
}

// Split-K fp32 GEMM with atomicAdd epilogue (tiny R1 GEMM; SK=8 -> 256 blocks).
__global__ __launch_bounds__(256)
void gemm64sk_kernel(const float* __restrict__ A, const float* __restrict__ B,
                     float* __restrict__ C, int M, int N, int K, int SK) {
  int zz = blockIdx.z;
  int b = zz / SK, kc = zz % SK;
  int kchunk = K / SK;
  int kbeg = kc * kchunk, kend = kbeg + kchunk;
  const float* Ab = A + (size_t)b * M * K;
  const float* Bb = B + (size_t)b * K * N;
  __shared__ float As[16][68];
  __shared__ float Bs[16][64];
  int row0 = blockIdx.y * 64;
  int col0 = blockIdx.x * 64;
  int t = threadIdx.x;
  int tx = t & 15, ty = t >> 4;
  float acc[4][4] = {};
  int la_r = t >> 2;
  int la_k = (t & 3) << 2;
  int lb_r = t >> 4;
  int lb_c = (t & 15) << 2;
  const float* Aptr = Ab + (size_t)(row0 + la_r) * K + la_k;
  const float* Bptr = Bb + (size_t)lb_r * N + col0 + lb_c;
  float4 av = *(const float4*)(Aptr + kbeg);
  float4 bv = *(const float4*)(Bptr + (size_t)kbeg * N);
  for (int k0 = kbeg; k0 < kend; k0 += 16) {
    __syncthreads();
    As[la_k + 0][la_r] = av.x;
    As[la_k + 1][la_r] = av.y;
    As[la_k + 2][la_r] = av.z;
    As[la_k + 3][la_r] = av.w;
    *(float4*)&Bs[lb_r][lb_c] = bv;
    __syncthreads();
    if (k0 + 16 < kend) {
      av = *(const float4*)(Aptr + k0 + 16);
      bv = *(const float4*)(Bptr + (size_t)(k0 + 16) * N);
    }
#pragma unroll
    for (int k = 0; k < 16; ++k) {
      float4 a = *(const float4*)&As[k][ty << 2];
      float4 bq = *(const float4*)&Bs[k][tx << 2];
      float av4[4] = {a.x, a.y, a.z, a.w};
      float bv4[4] = {bq.x, bq.y, bq.z, bq.w};
#pragma unroll
      for (int ii = 0; ii < 4; ++ii)
#pragma unroll
        for (int jj = 0; jj < 4; ++jj)
          acc[ii][jj] = fmaf(av4[ii], bv4[jj], acc[ii][jj]);
    }
  }
  float* Cb = C + (size_t)b * M * N;
#pragma unroll
  for (int ii = 0; ii < 4; ++ii)
#pragma unroll
    for (int jj = 0; jj < 4; ++jj)
      atomicAdd(&Cb[(size_t)(row0 + (ty << 2) + ii) * N + col0 + (tx << 2) + jj],
                acc[ii][jj]);
}

// ---- R2 split-f16 MFMA GEMM, now split-K x2 (grid 8x8x4 = 256 blocks;
// R9 showed 128 blocks left half the GPU idle). Same proven main loop;
// atomicAdd epilogue into zeroed R2.
__global__ __launch_bounds__(256, 2)
void mfma_r2_kernel(const _Float16* __restrict__ Ahi, const _Float16* __restrict__ Alo,
                    const _Float16* __restrict__ Bhi, const _Float16* __restrict__ Blo,
                    float* __restrict__ Cout) {
  const int K = 1152;
  int bx = blockIdx.x, by = blockIdx.y;
  int zz = blockIdx.z;
  int b = zz >> 1, kc = zz & 1;          // K-chunk: [kc*576, kc*576+576)
  int kbyte0 = kc * 1152;                 // byte offset of chunk start (576*2)
  int row0 = by * 128;
  int col0 = bx * 128;
  int t = threadIdx.x;
  int lane = t & 63, wave = t >> 6;
  int wy = wave & 1, wx = wave >> 1;
  int quad = lane >> 4, lm = lane & 15;

  __shared__ _Float16 lds[2 * 4 * 4096];

  int off[2];
#pragma unroll
  for (int h = 0; h < 2; ++h) {
    int d = wave * 128 + h * 64 + lane;
    int line = d >> 3;
    int c3 = (d & 7) ^ (line & 7);
    int row = (line << 1) | (c3 >> 2);
    int c = c3 & 3;
    off[h] = row * (K * 2) + c * 16;
  }
  const char* pg[4];
  pg[0] = (const char*)Ahi + ((size_t)b * 1024 + row0) * (size_t)K * 2;
  pg[1] = (const char*)Alo + ((size_t)b * 1024 + row0) * (size_t)K * 2;
  pg[2] = (const char*)Bhi + ((size_t)b * 1024 + col0) * (size_t)K * 2;
  pg[3] = (const char*)Blo + ((size_t)b * 1024 + col0) * (size_t)K * 2;

  int ra[4], rb[4];
#pragma unroll
  for (int i = 0; i < 4; ++i) {
    int rowa = wy * 64 + i * 16 + lm;
    int la_ = rowa >> 1;
    ra[i] = la_ * 128 + (((((rowa & 1) << 2) | quad) ^ (la_ & 7)) << 4);
    int rowb = wx * 64 + i * 16 + lm;
    int lb_ = rowb >> 1;
    rb[i] = lb_ * 128 + (((((rowb & 1) << 2) | quad) ^ (lb_ & 7)) << 4);
  }

  f32x4 S1[4][4] = {};
  f32x4 S2[4][4] = {};

#pragma unroll
  for (int p = 0; p < 4; ++p) {
    char* lb_ = (char*)lds + p * 8192 + wave * 2048;
    gload_lds16(pg[p] + kbyte0 + off[0], lb_);
    gload_lds16(pg[p] + kbyte0 + off[1], lb_ + 1024);
  }
  __syncthreads();

  int buf = 0;
  for (int tki = 0; tki < 18; ++tki) {
    const char* lb = (const char*)lds + buf * 32768;
    half8 aH[4], aL[4], bH[4], bL[4];
#pragma unroll
    for (int i = 0; i < 4; ++i) {
      aH[i] = *(const half8*)(lb + ra[i]);
      aL[i] = *(const half8*)(lb + 8192 + ra[i]);
      bH[i] = *(const half8*)(lb + 16384 + rb[i]);
      bL[i] = *(const half8*)(lb + 24576 + rb[i]);
    }
    if (tki < 17) {
      int kbyte = kbyte0 + (tki + 1) * 64;
#pragma unroll
      for (int p = 0; p < 4; ++p) {
        char* lw = (char*)lds + (buf ^ 1) * 32768 + p * 8192 + wave * 2048;
        gload_lds16(pg[p] + kbyte + off[0], lw);
        gload_lds16(pg[p] + kbyte + off[1], lw + 1024);
      }
    }
#pragma unroll
    for (int i = 0; i < 4; ++i)
#pragma unroll
      for (int j = 0; j < 4; ++j) {
        S1[i][j] = __builtin_amdgcn_mfma_f32_16x16x32_f16(aH[i], bH[j], S1[i][j], 0, 0, 0);
        S2[i][j] = __builtin_amdgcn_mfma_f32_16x16x32_f16(aH[i], bL[j], S2[i][j], 0, 0, 0);
        S2[i][j] = __builtin_amdgcn_mfma_f32_16x16x32_f16(aL[i], bH[j], S2[i][j], 0, 0, 0);
      }
    __syncthreads();
    buf ^= 1;
  }

  const float inv4096 = 1.0f / 4096.0f;
  float* Cb = Cout + (size_t)b * 1024 * 1024;
#pragma unroll
  for (int i = 0; i < 4; ++i)
#pragma unroll
    for (int j = 0; j < 4; ++j)
#pragma unroll
      for (int r = 0; r < 4; ++r) {
        int gn = row0 + wy * 64 + i * 16 + quad * 4 + r;
        int gm = col0 + wx * 64 + j * 16 + lm;
        atomicAdd(&Cb[(size_t)gn * 1024 + gm], S1[i][j][r] + S2[i][j][r] * inv4096);
      }
}

// MFMA split-f16 GEMM — EXACT R1 kernel (184us, MfmaUtil 27.5%). DO NOT TOUCH:
// epilogue restructures spill the K-loop accumulators (R2/R3: 650-700us, 1GB
// of scratch writes). Verified restored in R4/R5/R9.
__global__ __launch_bounds__(256, 2)
void mfma_fused_kernel(const _Float16* __restrict__ Ahi, const _Float16* __restrict__ Alo,
                       const _Float16* __restrict__ Bhi, const _Float16* __restrict__ Blo,
                       const float* __restrict__ up2, const float* __restrict__ up1,
                       unsigned long long* __restrict__ packed) {
  const int K = 576;
  int bid = (blockIdx.z * 32 + blockIdx.y) * 32 + blockIdx.x;
  int swz = (bid & 7) * 256 + (bid >> 3);
  int bx = swz & 31;
  int by = (swz >> 5) & 31;
  int b  = swz >> 10;

  int row0 = by * 128;
  int col0 = bx * 128;
  int t = threadIdx.x;
  int lane = t & 63, wave = t >> 6;
  int wy = wave & 1, wx = wave >> 1;
  int quad = lane >> 4, lm = lane & 15;

  __shared__ _Float16 lds[2 * 4 * 4096];

  int off[2];
#pragma unroll
  for (int h = 0; h < 2; ++h) {
    int d = wave * 128 + h * 64 + lane;
    int line = d >> 3;
    int c3 = (d & 7) ^ (line & 7);
    int row = (line << 1) | (c3 >> 2);
    int c = c3 & 3;
    off[h] = row * (K * 2) + c * 16;
  }
  const char* pg[4];
  pg[0] = (const char*)Ahi + ((size_t)b * 4096 + row0) * (size_t)K * 2;
  pg[1] = (const char*)Alo + ((size_t)b * 4096 + row0) * (size_t)K * 2;
  pg[2] = (const char*)Bhi + ((size_t)b * 4096 + col0) * (size_t)K * 2;
  pg[3] = (const char*)Blo + ((size_t)b * 4096 + col0) * (size_t)K * 2;

  int ra[4], rb[4];
#pragma unroll
  for (int i = 0; i < 4; ++i) {
    int rowa = wy * 64 + i * 16 + lm;
    int la_ = rowa >> 1;
    ra[i] = la_ * 128 + (((((rowa & 1) << 2) | quad) ^ (la_ & 7)) << 4);
    int rowb = wx * 64 + i * 16 + lm;
    int lb_ = rowb >> 1;
    rb[i] = lb_ * 128 + (((((rowb & 1) << 2) | quad) ^ (lb_ & 7)) << 4);
  }

  f32x4 S1[4][4] = {};
  f32x4 S2[4][4] = {};

#pragma unroll
  for (int p = 0; p < 4; ++p) {
    char* lb_ = (char*)lds + p * 8192 + wave * 2048;
    gload_lds16(pg[p] + off[0], lb_);
    gload_lds16(pg[p] + off[1], lb_ + 1024);
  }
  __syncthreads();

  int buf = 0;
  for (int t18 = 0; t18 < 18; ++t18) {
    const char* lb = (const char*)lds + buf * 32768;
    half8 aH[4], aL[4], bH[4], bL[4];
#pragma unroll
    for (int i = 0; i < 4; ++i) {
      aH[i] = *(const half8*)(lb + ra[i]);
      aL[i] = *(const half8*)(lb + 8192 + ra[i]);
      bH[i] = *(const half8*)(lb + 16384 + rb[i]);
      bL[i] = *(const half8*)(lb + 24576 + rb[i]);
    }
    if (t18 < 17) {
      int kbyte = (t18 + 1) * 64;
#pragma unroll
      for (int p = 0; p < 4; ++p) {
        char* lw = (char*)lds + (buf ^ 1) * 32768 + p * 8192 + wave * 2048;
        gload_lds16(pg[p] + kbyte + off[0], lw);
        gload_lds16(pg[p] + kbyte + off[1], lw + 1024);
      }
    }
#pragma unroll
    for (int i = 0; i < 4; ++i)
#pragma unroll
      for (int j = 0; j < 4; ++j) {
        S1[i][j] = __builtin_amdgcn_mfma_f32_16x16x32_f16(aH[i], bH[j], S1[i][j], 0, 0, 0);
        S2[i][j] = __builtin_amdgcn_mfma_f32_16x16x32_f16(aH[i], bL[j], S2[i][j], 0, 0, 0);
        S2[i][j] = __builtin_amdgcn_mfma_f32_16x16x32_f16(aL[i], bH[j], S2[i][j], 0, 0, 0);
      }
    __syncthreads();
    buf ^= 1;
  }

  const float inv4096 = 1.0f / 4096.0f;
  const float* u2b = up2 + (size_t)b * 4096 * 1024;
  const float* u1b = up1 + (size_t)b * 4096 * 256;
#pragma unroll
  for (int j = 0; j < 4; ++j) {
    int gm = col0 + wx * 64 + j * 16 + lm;
    float src2 = (gm + 0.5f) * 0.25f - 0.5f;
    float f2 = floorf(src2); float t2 = src2 - f2; int i2 = (int)f2;
    int idx2[4]; float w2[4];
#pragma unroll
    for (int tp = 0; tp < 4; ++tp) {
      idx2[tp] = min(max(i2 + tp - 1, 0), 1023);
      w2[tp] = cubicw(t2 - (float)(tp - 1));
    }
    float src1 = (gm + 0.5f) * 0.0625f - 0.5f;
    float f1 = floorf(src1); float t1 = src1 - f1; int i1 = (int)f1;
    int idx1[4]; float w1[4];
#pragma unroll
    for (int tp = 0; tp < 4; ++tp) {
      idx1[tp] = min(max(i1 + tp - 1, 0), 255);
      w1[tp] = cubicw(t1 - (float)(tp - 1));
    }
    unsigned long long best = 0ull;
#pragma unroll
    for (int i = 0; i < 4; ++i) {
#pragma unroll
      for (int r = 0; r < 4; ++r) {
        int gn = row0 + wy * 64 + i * 16 + quad * 4 + r;
        float v = S1[i][j][r] + S2[i][j][r] * inv4096;
        const float* r2row = u2b + (size_t)gn * 1024;
        const float* r1row = u1b + (size_t)gn * 256;
        v += w2[0] * r2row[idx2[0]] + w2[1] * r2row[idx2[1]]
           + w2[2] * r2row[idx2[2]] + w2[3] * r2row[idx2[3]];
        v += w1[0] * r1row[idx1[0]] + w1[1] * r1row[idx1[1]]
           + w1[2] * r1row[idx1[2]] + w1[3] * r1row[idx1[3]];
        v *= (1.0f / 3.0f);
        unsigned int fb = __float_as_uint(v);
        unsigned int key = (fb & 0x80000000u) ? ~fb : (fb | 0x80000000u);
        unsigned long long pk = ((unsigned long long)key << 32)
                              | (unsigned long long)(0xFFFFFFFFu - (unsigned)gn);
        best = best > pk ? best : pk;
      }
    }
    unsigned long long o;
    o = __shfl_xor(best, 16); best = best > o ? best : o;
    o = __shfl_xor(best, 32); best = best > o ? best : o;
    if (lane < 16) atomicMax(&packed[(size_t)b * 4096 + gm], best);
  }
}

__global__ void finalize_kernel(const unsigned long long* __restrict__ packed,
                                float* __restrict__ s3_out, int* __restrict__ arg, int total) {
  int i = blockIdx.x * blockDim.x + threadIdx.x;
  if (i >= total) return;
  unsigned long long pk = packed[i];
  unsigned int key = (unsigned int)(pk >> 32);
  unsigned int fb = (key & 0x80000000u) ? (key ^ 0x80000000u) : ~key;
  s3_out[i] = __uint_as_float(fb);
  arg[i] = (int)(0xFFFFFFFFu - (unsigned int)(pk & 0xFFFFFFFFull));
}

// ------------- batched multi-job 2D transpose (3 ref levels) -------------
__global__ __launch_bounds__(256)
void transpose_multi(const float* __restrict__ ref3, const float* __restrict__ ref2,
                     const float* __restrict__ ref1, float* __restrict__ o3,
                     float* __restrict__ o2, float* __restrict__ o1) {
  __shared__ float tile[32][33];
  int blk = blockIdx.x;
  const float* in; float* out; int R, S, gx, gy, base;
  if (blk < 2048)      { in = ref3; out = o3; R = 256; S = 4096;  gx = 128;  gy = 8; base = 0; }
  else if (blk < 6144) { in = ref2; out = o2; R = 128; S = 16384; gx = 512;  gy = 4; base = 2048; }
  else                 { in = ref1; out = o1; R = 64;  S = 65536; gx = 2048; gy = 2; base = 6144; }
  int local = blk - base;
  int pb = gx * gy;
  int b = local / pb;
  int rem = local % pb;
  int r0 = (rem / gx) * 32;
  int s0 = (rem % gx) * 32;
  int tx = threadIdx.x & 31, ty = threadIdx.x >> 5;
  const float* ib = in + (size_t)b * R * S;
  float* ob = out + (size_t)b * R * S;
#pragma unroll
  for (int k = 0; k < 4; ++k)
    tile[ty + 8 * k][tx] = ib[(size_t)(r0 + ty + 8 * k) * S + s0 + tx];
  __syncthreads();
#pragma unroll
  for (int k = 0; k < 4; ++k)
    ob[(size_t)(s0 + ty + 8 * k) * R + r0 + tx] = tile[tx][ty + 8 * k];
}

// ---- fold-gather body: channel-last float4 reads + fused channel-first store
template<int KK, int SS, int PP, int CL2, int WL2>
__device__ __forceinline__ void foldT_body(const float* __restrict__ refT,
                                           const int* __restrict__ arg,
                                           float* __restrict__ outCF,
                                           float* lds, int bx, int h, int b) {
  const int C = 1 << CL2, W = 1 << WL2;
  const int NK = (C / 4) / 16;
  int tid = threadIdx.x;
  int pl = tid >> 4, c4g = tid & 15;
  int w0 = bx * 16;
  int w = w0 + pl;
  int y = h + PP, x = w + PP;
  int ho_lo = (y - KK + 1) > 0 ? (y - KK + 1 + SS - 1) / SS : 0;
  int ho_hi = min(63, y / SS);
  int wo_lo = (x - KK + 1) > 0 ? (x - KK + 1 + SS - 1) / SS : 0;
  int wo_hi = min(63, x / SS);
  const int* argb = arg + b * 4096;
  const f32x4* refb4 = (const f32x4*)(refT + ((size_t)b << (2 * WL2 + CL2)));
  f32x4 acc[NK] = {};
  for (int ho = ho_lo; ho <= ho_hi; ++ho) {
    int ki = y - SS * ho;
    for (int wo = wo_lo; wo <= wo_hi; ++wo) {
      int kj = x - SS * wo;
      int q = argb[(ho << 6) + wo];
      int qh = q >> 6, qw = q & 63;
      int ry = SS * qh + ki - PP;
      int rx = SS * qw + kj - PP;
      if (ry >= 0 && ry < W && rx >= 0 && rx < W) {
        const f32x4* pb4 = refb4 + (((size_t)(ry << WL2) + rx) << (CL2 - 2));
#pragma unroll
        for (int k = 0; k < NK; ++k) acc[k] += pb4[c4g + k * 16];
      }
    }
  }
#pragma unroll
  for (int k = 0; k < NK; ++k) {
    int c4 = c4g + k * 16;
#pragma unroll
    for (int j = 0; j < 4; ++j)
      lds[(4 * c4 + j) * 17 + pl] = acc[k][j] * (1.0f / 9.0f);
  }
  __syncthreads();
  size_t ob = ((size_t)(b * C)) << (2 * WL2);
  for (int idx = tid; idx < C * 16; idx += 256) {
    int c = idx >> 4, j = idx & 15;
    outCF[ob + ((size_t)c << (2 * WL2)) + (h << WL2) + w0 + j] = lds[c * 17 + j];
  }
}

// one dispatch for all three fold levels:
// [0,512) T3 ; [512,2560) T2 ; [2560,10752) T1
__global__ __launch_bounds__(256)
void foldT_all(const float* __restrict__ refT3, const float* __restrict__ refT2,
               const float* __restrict__ refT1, const int* __restrict__ arg,
               float* __restrict__ T3, float* __restrict__ T2, float* __restrict__ T1) {
  __shared__ float lds[256 * 17];
  int blk = blockIdx.x;
  if (blk < 512) {
    int local = blk;
    foldT_body<3, 1, 1, 8, 6>(refT3, arg, T3, lds, local & 3, (local >> 2) & 63, local >> 8);
  } else if (blk < 2560) {
    int local = blk - 512;
    foldT_body<6, 2, 2, 7, 7>(refT2, arg, T2, lds, local & 7, (local >> 3) & 127, local >> 10);
  } else {
    int local = blk - 2560;
    foldT_body<12, 4, 4, 6, 8>(refT1, arg, T1, lds, local & 15, (local >> 4) & 255, local >> 12);
  }
}

extern "C" void kernel_launch(void* const* d_in, const int* in_sizes, int n_in,
                              void* d_out, int out_size, void* d_ws, size_t ws_size,
                              hipStream_t stream) {
  const float* lrsr1 = (const float*)d_in[0];
  const float* lrsr2 = (const float*)d_in[1];
  const float* lrsr3 = (const float*)d_in[2];
  const float* refsr1 = (const float*)d_in[3];
  const float* refsr2 = (const float*)d_in[4];
  const float* refsr3 = (const float*)d_in[5];
  const float* ref1 = (const float*)d_in[6];
  const float* ref2 = (const float*)d_in[7];
  const float* ref3 = (const float*)d_in[8];
  float* out = (float*)d_out;
  float* ws = (float*)d_ws;

  const int B = 2;
  size_t off_planes = 0;
  size_t off_pl2 = off_planes + (size_t)B * 4096 * 576 * 2; // 4 lvl3 half-planes
  size_t off_r1n = off_pl2 + (size_t)B * 1024 * 1152 * 2;   // 4 lvl2 half-planes
  size_t off_l1n = off_r1n + (size_t)B * 256 * 2304;
  size_t off_R2  = off_l1n + (size_t)B * 2304 * 256;
  size_t off_R1  = off_R2  + (size_t)B * 1024 * 1024;
  size_t off_up2 = off_R1  + (size_t)B * 256 * 256;     // [2,4096,1024]
  size_t off_up1 = off_up2 + (size_t)B * 4096 * 1024;   // [2,4096,256]
  size_t off_S   = off_up1 + (size_t)B * 4096 * 256;    // 21504 floats
  size_t off_invn= off_S   + 21504;                     // 21504 floats
  size_t off_pk  = off_invn+ 21504;                     // [2,4096] u64
  size_t off_arg = off_pk  + (size_t)B * 4096 * 2;      // [2,4096] int

  const size_t PLANE3 = (size_t)B * 4096 * 576;   // halves per lvl3 plane
  _Float16* r3hi = (_Float16*)(ws + off_planes);
  _Float16* r3lo = r3hi + PLANE3;
  _Float16* l3hi = r3lo + PLANE3;
  _Float16* l3lo = l3hi + PLANE3;
  const size_t PLANE2 = (size_t)B * 1024 * 1152;  // halves per lvl2 plane
  _Float16* r2hi = (_Float16*)(ws + off_pl2);
  _Float16* r2lo = r2hi + PLANE2;
  _Float16* l2hi = r2lo + PLANE2;
  _Float16* l2lo = l2hi + PLANE2;

  unsigned long long* pk = (unsigned long long*)(ws + off_pk);
  int* argp = (int*)(ws + off_arg);

  // 1. zero R1 + packed + R2 + S (S for atomic sumsq, R2 for split-K mfma)
  init_multi<<<DIVUP(65536 + 8192 + 1048576 + 21504, 256), 256, 0, stream>>>(
      (unsigned long long*)(ws + off_R1), pk,
      (unsigned long long*)(ws + off_R2), (unsigned long long*)(ws + off_S));
  // 2-3. norms for all 6 descriptor inputs (sumsq now x8 channel-parallel)
  sumsq_multi<<<84 * 8, 256, 0, stream>>>(refsr3, lrsr3, refsr2, lrsr2, refsr1, lrsr1,
                                          ws + off_S);
  invnorm_multi<<<84, 256, 0, stream>>>(ws + off_S, ws + off_invn);
  // 4. split-f16 descriptors for levels 3 and 2 (pixel-major)
  desc_split_multi<<<6144, 256, 0, stream>>>(refsr3, lrsr3, refsr2, lrsr2,
                                             r3hi, r3lo, l3hi, l3lo,
                                             r2hi, r2lo, l2hi, l2lo,
                                             ws + off_invn);
  // 5. level-1 fp32 descriptors (both layouts, one dispatch)
  desc_f32_multi<<<9216, 256, 0, stream>>>(lrsr1, refsr1, ws + off_l1n, ws + off_r1n,
                                           ws + off_invn);
  // 6. R2 via split-f16 MFMA, split-K x2 -> 256 blocks
  {
    dim3 g(8, 8, B * 2);
    mfma_r2_kernel<<<g, 256, 0, stream>>>(r2hi, r2lo, l2hi, l2lo, ws + off_R2);
  }
  // 7. R1 via fp32 split-K
  {
    dim3 g(256 / 64, 256 / 64, B * 8);
    gemm64sk_kernel<<<g, 256, 0, stream>>>(ws + off_r1n, ws + off_l1n, ws + off_R1,
                                           256, 256, 2304, 8);
  }
  // 8. both bicubic row-upsamples
  upsample_multi<<<40960, 256, 0, stream>>>(ws + off_R2, ws + off_R1,
                                            ws + off_up2, ws + off_up1);
  // 9. fused R3 MFMA GEMM + bicubic add + max/argmax
  {
    dim3 g(4096 / 128, 4096 / 128, B);
    mfma_fused_kernel<<<g, 256, 0, stream>>>(r3hi, r3lo, l3hi, l3lo,
                                             ws + off_up2, ws + off_up1, pk);
  }
  // 10. unpack S_3 / argmax
  finalize_kernel<<<DIVUP(B * 4096, 256), 256, 0, stream>>>(pk, out, argp, B * 4096);

  // 11. batched channel-last transposes of ref1/2/3 into dead ws regions
  float* refT3 = ws + off_planes;                 // 2,097,152 floats
  float* refT2 = refT3 + (size_t)2 * 256 * 4096;  // 4,194,304 floats
  float* refT1 = ws + off_up2;                    // 8,388,608 floats
  transpose_multi<<<14336, 256, 0, stream>>>(ref3, ref2, ref1, refT3, refT2, refT1);

  // 12. all three fold-gathers in one dispatch
  float* T3 = out + 8192;
  float* T2 = T3 + (size_t)B * 256 * 64 * 64;
  float* T1 = T2 + (size_t)B * 128 * 128 * 128;
  foldT_all<<<10752, 256, 0, stream>>>(refT3, refT2, refT1, argp, T3, T2, T1);
}